// Round 7
// baseline (328.196 us; speedup 1.0000x reference)
//
#include <hip/hip_runtime.h>
#include <hip/hip_bf16.h>

// ---------------------------------------------------------------------------
// GAT 2-layer forward. N=50000, E=800000 (+N self loops).
// Round 7: k_fill scatter slimmed — (src,dst) packed into ONE int2 store
// (R6 profile: two 4B stores to separate arrays caused 84MB writeback, 12x
// amplification), rowptr folded into cursor (atomicAdd returns pos directly).
// Precomputed per-(edge,head) weights; gather+FMA aggregator; bf16 features;
// MFMA GEMMs.
// ---------------------------------------------------------------------------

typedef __attribute__((ext_vector_type(8))) short bf16x8;
typedef __attribute__((ext_vector_type(4))) float f32x4;

__device__ __forceinline__ unsigned short f2bf(float f) {
  unsigned x = __float_as_uint(f);
  unsigned r = (x + 0x7fffu + ((x >> 16) & 1u)) >> 16;  // RNE
  return (unsigned short)r;
}
__device__ __forceinline__ float bflo(unsigned u) {
  return __uint_as_float(u << 16);
}
__device__ __forceinline__ float bfhi(unsigned u) {
  return __uint_as_float(u & 0xffff0000u);
}

// ---- weight conversions: W1[128][128] + W2[128][64] -> bf16 transposed -----
__global__ void cvt_w2(const float* __restrict__ W1, unsigned short* __restrict__ W1t,
                       const float* __restrict__ W2, unsigned short* __restrict__ W2t) {
  int i = blockIdx.x * blockDim.x + threadIdx.x;
  if (i < 128 * 128) {
    int k = i >> 7, m = i & 127;
    W1t[m * 128 + k] = f2bf(W1[i]);
  } else if (i < 128 * 128 + 128 * 64) {
    int j = i - 128 * 128;
    int k = j / 64, m = j % 64;
    W2t[m * 128 + k] = f2bf(W2[j]);
  }
}

// ---- MFMA GEMM: C[N][M] bf16 = A[N][128] @ Bt[M][128]^T --------------------
// AF32: A is f32 (converted to bf16 in-register). One wave per 16 rows.
template <int AF32>
__global__ __launch_bounds__(256) void gemm_mfma(
    const void* __restrict__ Av, const unsigned short* __restrict__ Bt,
    unsigned short* __restrict__ C, int N, int M) {
  const int K = 128;
  int lane = threadIdx.x & 63;
  int wv = threadIdx.x >> 6;
  int row0 = blockIdx.x * 64 + wv * 16;
  if (row0 >= N) return;  // N % 16 == 0
  int r = lane & 15, quad = lane >> 4;

  bf16x8 a[4];
  if (AF32) {
    const float* ap = (const float*)Av + (size_t)(row0 + r) * K + quad * 8;
#pragma unroll
    for (int t = 0; t < 4; ++t) {
      float4 lo = *(const float4*)(ap + t * 32);
      float4 hi = *(const float4*)(ap + t * 32 + 4);
      a[t][0] = (short)f2bf(lo.x); a[t][1] = (short)f2bf(lo.y);
      a[t][2] = (short)f2bf(lo.z); a[t][3] = (short)f2bf(lo.w);
      a[t][4] = (short)f2bf(hi.x); a[t][5] = (short)f2bf(hi.y);
      a[t][6] = (short)f2bf(hi.z); a[t][7] = (short)f2bf(hi.w);
    }
  } else {
    const unsigned short* ap = (const unsigned short*)Av + (size_t)(row0 + r) * K + quad * 8;
#pragma unroll
    for (int t = 0; t < 4; ++t) a[t] = *(const bf16x8*)(ap + t * 32);
  }

  for (int c0 = 0; c0 < M; c0 += 16) {
    f32x4 acc = {0.f, 0.f, 0.f, 0.f};
    const unsigned short* bp = Bt + (size_t)(c0 + r) * K + quad * 8;
#pragma unroll
    for (int t = 0; t < 4; ++t) {
      bf16x8 b = *(const bf16x8*)(bp + t * 32);
      acc = __builtin_amdgcn_mfma_f32_16x16x32_bf16(a[t], b, acc, 0, 0, 0);
    }
    unsigned short* cp = C + (size_t)(row0 + quad * 4) * M + c0 + r;
#pragma unroll
    for (int i = 0; i < 4; ++i) cp[(size_t)i * M] = f2bf(acc[i]);
  }
}

// ---- attention scores (bf16 input) -----------------------------------------
__global__ void att_scores_bf(const unsigned short* __restrict__ h,
                              const float* __restrict__ a_src,
                              const float* __restrict__ a_dst,
                              float* __restrict__ ssrc, float* __restrict__ sdst,
                              int N, int H, int C) {
  int idx = blockIdx.x * blockDim.x + threadIdx.x;
  if (idx >= N * H) return;
  int n = idx / H, hh = idx % H;
  const unsigned short* hp = h + (size_t)n * H * C + (size_t)hh * C;
  const float* as = a_src + hh * C;
  const float* ad = a_dst + hh * C;
  float s1 = 0.f, s2 = 0.f;
  for (int c = 0; c < C; c += 2) {
    unsigned u = *(const unsigned*)(hp + c);
    float f0 = bflo(u), f1 = bfhi(u);
    s1 = fmaf(f0, as[c], fmaf(f1, as[c + 1], s1));
    s2 = fmaf(f0, ad[c], fmaf(f1, ad[c + 1], s2));
  }
  ssrc[idx] = s1;
  sdst[idx] = s2;
}

// ---- CSR build --------------------------------------------------------------

__global__ void k_deg(const int* __restrict__ ei, int E, int N, int* __restrict__ deg) {
  int e = blockIdx.x * blockDim.x + threadIdx.x;
  if (e >= E + N) return;
  int d = (e < E) ? ei[E + e] : (e - E);
  atomicAdd(deg + d, 1);
}

__global__ __launch_bounds__(256) void k_scan_block(const int* __restrict__ in,
                                                    int* __restrict__ out_part,
                                                    int* __restrict__ bsum, int n) {
  int tid = threadIdx.x, lane = tid & 63, wv = tid >> 6;
  int i = blockIdx.x * 256 + tid;
  int v = (i < n) ? in[i] : 0;
  int x = v;
#pragma unroll
  for (int off = 1; off < 64; off <<= 1) {
    int y = __shfl_up(x, off);
    if (lane >= off) x += y;
  }
  __shared__ int ws[4];
  if (lane == 63) ws[wv] = x;
  __syncthreads();
  int wo = 0;
  for (int w = 0; w < wv; ++w) wo += ws[w];
  if (i < n) out_part[i] = wo + x - v;
  if (tid == 255 && bsum) bsum[blockIdx.x] = wo + x;
}

// rowptr[i] += boff[block]; cursor[i] = rowptr[i] (k_fill atomics on cursor
// then return the slot directly — no rowptr read in k_fill)
__global__ void k_scan_add(int* __restrict__ rowptr, int* __restrict__ cursor,
                           const int* __restrict__ boff, int n, int total) {
  int i = blockIdx.x * blockDim.x + threadIdx.x;
  if (i < n) {
    int v = rowptr[i] + boff[blockIdx.x];
    rowptr[i] = v;
    cursor[i] = v;
  }
  if (i == 0) rowptr[n] = total;
}

// scatter: one packed int2 (src,dst) per CSR slot (single dirty line/edge)
__global__ void k_fill(const int* __restrict__ ei, int E, int N,
                       int* __restrict__ cursor, int2* __restrict__ csr2) {
  int e = blockIdx.x * blockDim.x + threadIdx.x;
  if (e >= E + N) return;
  int s, d;
  if (e < E) {
    s = ei[e];
    d = ei[E + e];
  } else {
    s = e - E;
    d = s;
  }
  int pos = atomicAdd(cursor + d, 1);
  csr2[pos] = make_int2(s, d);
}

// ---- per-(edge,head) softmax weights, coalesced over CSR slots --------------
template <int H>
__global__ void k_weights(const int2* __restrict__ csr2, int ET,
                          const float* __restrict__ ssrc,
                          const float* __restrict__ sdst, float* __restrict__ ew) {
  int i = blockIdx.x * blockDim.x + threadIdx.x;
  if (i >= ET) return;
  int2 p = csr2[i];
  int s = p.x, d = p.y;
  if (H == 4) {
    float4 a = *(const float4*)(ssrc + (size_t)s * 4);
    float4 b = *(const float4*)(sdst + (size_t)d * 4);
    float4 w;
    float sc;
    sc = a.x + b.x; sc = sc > 0.f ? sc : 0.2f * sc; w.x = __expf(sc);
    sc = a.y + b.y; sc = sc > 0.f ? sc : 0.2f * sc; w.y = __expf(sc);
    sc = a.z + b.z; sc = sc > 0.f ? sc : 0.2f * sc; w.z = __expf(sc);
    sc = a.w + b.w; sc = sc > 0.f ? sc : 0.2f * sc; w.w = __expf(sc);
    *(float4*)(ew + (size_t)i * 4) = w;
  } else {
    float sc = ssrc[s] + sdst[d];
    sc = sc > 0.f ? sc : 0.2f * sc;
    ew[i] = __expf(sc);
  }
}

// ---- aggregator: out[n] = (sum_e w_e * h[src_e]) / (sum_e w_e) + bias -------
// One wave per dst node. L lanes per edge (4 bf16 ch each); G=64/L edge
// groups per wave. Group g handles CSR slots beg+g, beg+g+G, ... with direct
// (group-uniform-address) csr/ew loads; manual 2-deep load pipeline.
// Cross-group combine via reconvergent shfl_xor butterfly at the end.
template <int H, int C, int L, int OUT_BF16>
__global__ __launch_bounds__(256) void gat_aggr3(
    const int* __restrict__ rowptr, const int2* __restrict__ csr2,
    const float* __restrict__ ew, const unsigned short* __restrict__ h,
    const float* __restrict__ bias, void* __restrict__ outv, int N) {
  const int HC = H * C;
  const int G = 64 / L;  // edge groups per wave
  int lane = threadIdx.x & 63;
  int n = blockIdx.x * 4 + (threadIdx.x >> 6);
  if (n >= N) return;
  int l = lane & (L - 1);
  int g = lane / L;
  int c0 = l * 4;
  int hh = c0 / C;
  int beg = rowptr[n];
  int cnt = rowptr[n + 1] - beg;
  float a0 = 0.f, a1 = 0.f, a2 = 0.f, a3 = 0.f, ws = 0.f;

  int j = g;
  for (; j + G < cnt; j += 2 * G) {
    int i0 = beg + j, i1 = beg + j + G;
    int s0 = csr2[i0].x;
    int s1 = csr2[i1].x;
    float w0 = ew[(size_t)i0 * H + hh];
    float w1 = ew[(size_t)i1 * H + hh];
    uint2 u0 = *(const uint2*)(h + (size_t)s0 * HC + c0);
    uint2 u1 = *(const uint2*)(h + (size_t)s1 * HC + c0);
    a0 = fmaf(w0, bflo(u0.x), a0);
    a1 = fmaf(w0, bfhi(u0.x), a1);
    a2 = fmaf(w0, bflo(u0.y), a2);
    a3 = fmaf(w0, bfhi(u0.y), a3);
    a0 = fmaf(w1, bflo(u1.x), a0);
    a1 = fmaf(w1, bfhi(u1.x), a1);
    a2 = fmaf(w1, bflo(u1.y), a2);
    a3 = fmaf(w1, bfhi(u1.y), a3);
    ws += w0 + w1;
  }
  if (j < cnt) {  // at most one group-iteration remains
    int i0 = beg + j;
    int s0 = csr2[i0].x;
    float w0 = ew[(size_t)i0 * H + hh];
    uint2 u0 = *(const uint2*)(h + (size_t)s0 * HC + c0);
    a0 = fmaf(w0, bflo(u0.x), a0);
    a1 = fmaf(w0, bfhi(u0.x), a1);
    a2 = fmaf(w0, bflo(u0.y), a2);
    a3 = fmaf(w0, bfhi(u0.y), a3);
    ws += w0;
  }
#pragma unroll
  for (int off = L; off < 64; off <<= 1) {
    a0 += __shfl_xor(a0, off, 64);
    a1 += __shfl_xor(a1, off, 64);
    a2 += __shfl_xor(a2, off, 64);
    a3 += __shfl_xor(a3, off, 64);
    ws += __shfl_xor(ws, off, 64);
  }
  if (lane < L) {
    float inv = 1.f / ws;  // self-loop guarantees ws > 0
    float v0 = fmaf(a0, inv, bias[c0 + 0]);
    float v1 = fmaf(a1, inv, bias[c0 + 1]);
    float v2 = fmaf(a2, inv, bias[c0 + 2]);
    float v3 = fmaf(a3, inv, bias[c0 + 3]);
    if (OUT_BF16) {
      v0 = fmaxf(v0, 0.f); v1 = fmaxf(v1, 0.f);
      v2 = fmaxf(v2, 0.f); v3 = fmaxf(v3, 0.f);
      unsigned lo = (unsigned)f2bf(v0) | ((unsigned)f2bf(v1) << 16);
      unsigned hi = (unsigned)f2bf(v2) | ((unsigned)f2bf(v3) << 16);
      ((uint2*)outv)[(size_t)n * (HC / 4) + l] = make_uint2(lo, hi);
    } else {
      ((float4*)outv)[(size_t)n * (HC / 4) + l] = make_float4(v0, v1, v2, v3);
    }
  }
}

extern "C" void kernel_launch(void* const* d_in, const int* in_sizes, int n_in,
                              void* d_out, int out_size, void* d_ws, size_t ws_size,
                              hipStream_t stream) {
  const float* x   = (const float*)d_in[0];
  const int*   ei  = (const int*)d_in[1];
  const float* W1  = (const float*)d_in[2];
  const float* as1 = (const float*)d_in[3];
  const float* ad1 = (const float*)d_in[4];
  const float* b1  = (const float*)d_in[5];
  const float* W2  = (const float*)d_in[6];
  const float* as2 = (const float*)d_in[7];
  const float* ad2 = (const float*)d_in[8];
  const float* b2  = (const float*)d_in[9];

  const int N = in_sizes[0] / 128;  // 50000
  const int E = in_sizes[1] / 2;    // 800000
  const int ET = E + N;
  const int NB = (N + 255) / 256;

  char* pc = (char*)d_ws;
  auto alloc = [&](size_t bytes) -> void* {
    void* r = (void*)pc;
    pc += (bytes + 255) & ~(size_t)255;
    return r;
  };
  unsigned short* h1b   = (unsigned short*)alloc((size_t)N * 128 * 2);  // reused as h2b
  unsigned short* out1b = (unsigned short*)alloc((size_t)N * 128 * 2);
  unsigned short* W1t   = (unsigned short*)alloc(128 * 128 * 2);
  unsigned short* W2t   = (unsigned short*)alloc(64 * 128 * 2);
  float* ssrc1 = (float*)alloc((size_t)N * 4 * 4);
  float* sdst1 = (float*)alloc((size_t)N * 4 * 4);
  float* ssrc2 = (float*)alloc((size_t)N * 4);
  float* sdst2 = (float*)alloc((size_t)N * 4);
  int* rowptr = (int*)alloc((size_t)(N + 1) * 4);
  int* deg    = (int*)alloc((size_t)N * 4);
  int* cursor = (int*)alloc((size_t)N * 4);  // init by k_scan_add, no memset
  int* bsum   = (int*)alloc((size_t)NB * 4);
  int* boff   = (int*)alloc((size_t)NB * 4);
  int2* csr2  = (int2*)alloc((size_t)ET * 8);
  float* ew1  = (float*)alloc((size_t)ET * 4 * 4);
  float* ew2  = (float*)alloc((size_t)ET * 4);
  unsigned short* h2b = h1b;  // alias: h1b dead after layer-1 aggregation

  // zero the full padded deg region (cursor is fully written by k_scan_add)
  hipMemsetAsync(deg, 0, (size_t)((char*)cursor - (char*)deg), stream);

  dim3 blk(256);

  // ---- CSR build (shared by both layers) ----
  k_deg<<<dim3((ET + 255) / 256), blk, 0, stream>>>(ei, E, N, deg);
  k_scan_block<<<dim3(NB), blk, 0, stream>>>(deg, rowptr, bsum, N);
  k_scan_block<<<dim3(1), blk, 0, stream>>>(bsum, boff, nullptr, NB);
  k_scan_add<<<dim3(NB), blk, 0, stream>>>(rowptr, cursor, boff, N, ET);
  k_fill<<<dim3((ET + 255) / 256), blk, 0, stream>>>(ei, E, N, cursor, csr2);

  cvt_w2<<<dim3((128 * 128 + 128 * 64 + 255) / 256), blk, 0, stream>>>(W1, W1t, W2, W2t);

  // ---- layer 1: 128 -> 4 heads x 32, concat, +bias, ReLU ----
  gemm_mfma<1><<<dim3((N + 63) / 64), blk, 0, stream>>>(x, W1t, h1b, N, 128);
  att_scores_bf<<<dim3((N * 4 + 255) / 256), blk, 0, stream>>>(h1b, as1, ad1, ssrc1, sdst1, N, 4, 32);
  k_weights<4><<<dim3((ET + 255) / 256), blk, 0, stream>>>(csr2, ET, ssrc1, sdst1, ew1);
  gat_aggr3<4, 32, 32, 1><<<dim3((N + 3) / 4), blk, 0, stream>>>(
      rowptr, csr2, ew1, h1b, b1, out1b, N);

  // ---- layer 2: 128 -> 1 head x 64, +bias ----
  gemm_mfma<0><<<dim3((N + 63) / 64), blk, 0, stream>>>(out1b, W2t, h2b, N, 64);
  att_scores_bf<<<dim3((N + 255) / 256), blk, 0, stream>>>(h2b, as2, ad2, ssrc2, sdst2, N, 1, 64);
  k_weights<1><<<dim3((ET + 255) / 256), blk, 0, stream>>>(csr2, ET, ssrc2, sdst2, ew2);
  gat_aggr3<1, 64, 16, 0><<<dim3((N + 3) / 4), blk, 0, stream>>>(
      rowptr, csr2, ew2, h2b, b2, d_out, N);
}

// Round 8
// 302.230 us; speedup vs baseline: 1.0859x; 1.0859x over previous
//
#include <hip/hip_runtime.h>
#include <hip/hip_bf16.h>

// ---------------------------------------------------------------------------
// GAT 2-layer forward. N=50000, E=800000 (+N self loops).
// Round 8: CSR build rebuilt as two-level binning (hist -> scan -> chunked
// bin-scatter -> per-bucket LDS sort). R7 evidence: k_fill's random scatter
// dirtied every line in ~all 8 XCD L2s (WRITE 54MB = 8x payload) and
// cursor atomics ping-ponged cross-XCD; fix is block-private runs + LDS
// atomics, not fewer bytes. Aggregation/GEMM path unchanged from R7.
// Assumes N <= 65536 (bucket = dst>>8, <=256 buckets).
// ---------------------------------------------------------------------------

typedef __attribute__((ext_vector_type(8))) short bf16x8;
typedef __attribute__((ext_vector_type(4))) float f32x4;

__device__ __forceinline__ unsigned short f2bf(float f) {
  unsigned x = __float_as_uint(f);
  unsigned r = (x + 0x7fffu + ((x >> 16) & 1u)) >> 16;  // RNE
  return (unsigned short)r;
}
__device__ __forceinline__ float bflo(unsigned u) {
  return __uint_as_float(u << 16);
}
__device__ __forceinline__ float bfhi(unsigned u) {
  return __uint_as_float(u & 0xffff0000u);
}

// ---- weight conversions: W1[128][128] + W2[128][64] -> bf16 transposed -----
__global__ void cvt_w2(const float* __restrict__ W1, unsigned short* __restrict__ W1t,
                       const float* __restrict__ W2, unsigned short* __restrict__ W2t) {
  int i = blockIdx.x * blockDim.x + threadIdx.x;
  if (i < 128 * 128) {
    int k = i >> 7, m = i & 127;
    W1t[m * 128 + k] = f2bf(W1[i]);
  } else if (i < 128 * 128 + 128 * 64) {
    int j = i - 128 * 128;
    int k = j / 64, m = j % 64;
    W2t[m * 128 + k] = f2bf(W2[j]);
  }
}

// ---- MFMA GEMM: C[N][M] bf16 = A[N][128] @ Bt[M][128]^T --------------------
template <int AF32>
__global__ __launch_bounds__(256) void gemm_mfma(
    const void* __restrict__ Av, const unsigned short* __restrict__ Bt,
    unsigned short* __restrict__ C, int N, int M) {
  const int K = 128;
  int lane = threadIdx.x & 63;
  int wv = threadIdx.x >> 6;
  int row0 = blockIdx.x * 64 + wv * 16;
  if (row0 >= N) return;  // N % 16 == 0
  int r = lane & 15, quad = lane >> 4;

  bf16x8 a[4];
  if (AF32) {
    const float* ap = (const float*)Av + (size_t)(row0 + r) * K + quad * 8;
#pragma unroll
    for (int t = 0; t < 4; ++t) {
      float4 lo = *(const float4*)(ap + t * 32);
      float4 hi = *(const float4*)(ap + t * 32 + 4);
      a[t][0] = (short)f2bf(lo.x); a[t][1] = (short)f2bf(lo.y);
      a[t][2] = (short)f2bf(lo.z); a[t][3] = (short)f2bf(lo.w);
      a[t][4] = (short)f2bf(hi.x); a[t][5] = (short)f2bf(hi.y);
      a[t][6] = (short)f2bf(hi.z); a[t][7] = (short)f2bf(hi.w);
    }
  } else {
    const unsigned short* ap = (const unsigned short*)Av + (size_t)(row0 + r) * K + quad * 8;
#pragma unroll
    for (int t = 0; t < 4; ++t) a[t] = *(const bf16x8*)(ap + t * 32);
  }

  for (int c0 = 0; c0 < M; c0 += 16) {
    f32x4 acc = {0.f, 0.f, 0.f, 0.f};
    const unsigned short* bp = Bt + (size_t)(c0 + r) * K + quad * 8;
#pragma unroll
    for (int t = 0; t < 4; ++t) {
      bf16x8 b = *(const bf16x8*)(bp + t * 32);
      acc = __builtin_amdgcn_mfma_f32_16x16x32_bf16(a[t], b, acc, 0, 0, 0);
    }
    unsigned short* cp = C + (size_t)(row0 + quad * 4) * M + c0 + r;
#pragma unroll
    for (int i = 0; i < 4; ++i) cp[(size_t)i * M] = f2bf(acc[i]);
  }
}

// ---- attention scores (bf16 input) -----------------------------------------
__global__ void att_scores_bf(const unsigned short* __restrict__ h,
                              const float* __restrict__ a_src,
                              const float* __restrict__ a_dst,
                              float* __restrict__ ssrc, float* __restrict__ sdst,
                              int N, int H, int C) {
  int idx = blockIdx.x * blockDim.x + threadIdx.x;
  if (idx >= N * H) return;
  int n = idx / H, hh = idx % H;
  const unsigned short* hp = h + (size_t)n * H * C + (size_t)hh * C;
  const float* as = a_src + hh * C;
  const float* ad = a_dst + hh * C;
  float s1 = 0.f, s2 = 0.f;
  for (int c = 0; c < C; c += 2) {
    unsigned u = *(const unsigned*)(hp + c);
    float f0 = bflo(u), f1 = bfhi(u);
    s1 = fmaf(f0, as[c], fmaf(f1, as[c + 1], s1));
    s2 = fmaf(f0, ad[c], fmaf(f1, ad[c + 1], s2));
  }
  ssrc[idx] = s1;
  sdst[idx] = s2;
}

// ---- binned CSR build -------------------------------------------------------
// bucket b covers dst in [b*256, b*256+256)

// B1: global bucket histogram (LDS-staged; one global atomic/bucket/block)
__global__ __launch_bounds__(256) void b_hist(const int* __restrict__ ei, int E, int N,
                                              int* __restrict__ bucketCnt) {
  __shared__ int hcnt[256];
  int tid = threadIdx.x;
  hcnt[tid] = 0;
  __syncthreads();
  int ET = E + N;
  for (int e = blockIdx.x * 256 + tid; e < ET; e += gridDim.x * 256) {
    int d = (e < E) ? ei[E + e] : (e - E);
    atomicAdd(&hcnt[d >> 8], 1);
  }
  __syncthreads();
  int c = hcnt[tid];
  if (c > 0) atomicAdd(&bucketCnt[tid], c);
}

// B2: single-block exclusive scan of bucketCnt[256] -> bucketBase[257]
__global__ __launch_bounds__(256) void b_scan(const int* __restrict__ bucketCnt,
                                              int* __restrict__ bucketBase,
                                              int* __restrict__ bucketCur, int ET) {
  __shared__ int s[256];
  int tid = threadIdx.x;
  int v = bucketCnt[tid];
  s[tid] = v;
  __syncthreads();
  for (int o = 1; o < 256; o <<= 1) {
    int t = (tid >= o) ? s[tid - o] : 0;
    __syncthreads();
    s[tid] += t;
    __syncthreads();
  }
  bucketBase[tid] = s[tid] - v;
  bucketCur[tid] = 0;
  if (tid == 255) bucketBase[256] = ET;
}

// B3: chunked bin-scatter. Each block owns CHUNK consecutive edges; reserves
// one contiguous run per bucket (1 global atomic/bucket/block) and writes
// edges into its private runs -> each 64B line dirtied by one block/XCD.
#define CHUNK (64 * 256)
__global__ __launch_bounds__(256) void b_binscatter(
    const int* __restrict__ ei, int E, int N,
    const int* __restrict__ bucketBase, int* __restrict__ bucketCur,
    int2* __restrict__ bkt) {
  __shared__ int lcnt[256];
  __shared__ int lcur[256];
  int tid = threadIdx.x;
  lcnt[tid] = 0;
  __syncthreads();
  int ET = E + N;
  int base = blockIdx.x * CHUNK;
  int lim = base + CHUNK;
  if (lim > ET) lim = ET;
  // pass 1: count (dst only)
  for (int i = base + tid; i < lim; i += 256) {
    int d = (i < E) ? ei[E + i] : (i - E);
    atomicAdd(&lcnt[d >> 8], 1);
  }
  __syncthreads();
  int c = lcnt[tid];
  if (c > 0) lcur[tid] = bucketBase[tid] + atomicAdd(&bucketCur[tid], c);
  __syncthreads();
  // pass 2: scatter into this block's private runs
  for (int i = base + tid; i < lim; i += 256) {
    int s, d;
    if (i < E) {
      s = ei[i];
      d = ei[E + i];
    } else {
      s = i - E;
      d = s;
    }
    int slot = atomicAdd(&lcur[d >> 8], 1);
    bkt[slot] = make_int2(s, d);
  }
}

// B4: one block per bucket: LDS count+scan over the bucket's 256 nodes,
// coalesced rowptr write, then block-local scatter into csr2.
__global__ __launch_bounds__(256) void b_bucketsort(
    const int2* __restrict__ bkt, const int* __restrict__ bucketBase,
    int2* __restrict__ csr2, int* __restrict__ rowptr, int N, int ET) {
  __shared__ int cnt[256];
  __shared__ int s[256];
  int b = blockIdx.x, tid = threadIdx.x;
  int base = bucketBase[b], end = bucketBase[b + 1];
  cnt[tid] = 0;
  __syncthreads();
  for (int i = base + tid; i < end; i += 256) atomicAdd(&cnt[bkt[i].y & 255], 1);
  __syncthreads();
  int v = cnt[tid];
  s[tid] = v;
  __syncthreads();
  for (int o = 1; o < 256; o <<= 1) {
    int t = (tid >= o) ? s[tid - o] : 0;
    __syncthreads();
    s[tid] += t;
    __syncthreads();
  }
  int excl = s[tid] - v;
  int node = (b << 8) + tid;
  if (node < N) rowptr[node] = base + excl;
  if (tid == 0 && b == gridDim.x - 1) rowptr[N] = ET;
  cnt[tid] = base + excl;  // becomes the scatter cursor
  __syncthreads();
  for (int i = base + tid; i < end; i += 256) {
    int2 p = bkt[i];
    int slot = atomicAdd(&cnt[p.y & 255], 1);
    csr2[slot] = p;
  }
}

// ---- per-(edge,head) softmax weights, coalesced over CSR slots --------------
template <int H>
__global__ void k_weights(const int2* __restrict__ csr2, int ET,
                          const float* __restrict__ ssrc,
                          const float* __restrict__ sdst, float* __restrict__ ew) {
  int i = blockIdx.x * blockDim.x + threadIdx.x;
  if (i >= ET) return;
  int2 p = csr2[i];
  int s = p.x, d = p.y;
  if (H == 4) {
    float4 a = *(const float4*)(ssrc + (size_t)s * 4);
    float4 b = *(const float4*)(sdst + (size_t)d * 4);
    float4 w;
    float sc;
    sc = a.x + b.x; sc = sc > 0.f ? sc : 0.2f * sc; w.x = __expf(sc);
    sc = a.y + b.y; sc = sc > 0.f ? sc : 0.2f * sc; w.y = __expf(sc);
    sc = a.z + b.z; sc = sc > 0.f ? sc : 0.2f * sc; w.z = __expf(sc);
    sc = a.w + b.w; sc = sc > 0.f ? sc : 0.2f * sc; w.w = __expf(sc);
    *(float4*)(ew + (size_t)i * 4) = w;
  } else {
    float sc = ssrc[s] + sdst[d];
    sc = sc > 0.f ? sc : 0.2f * sc;
    ew[i] = __expf(sc);
  }
}

// ---- aggregator: out[n] = (sum_e w_e * h[src_e]) / (sum_e w_e) + bias -------
template <int H, int C, int L, int OUT_BF16>
__global__ __launch_bounds__(256) void gat_aggr3(
    const int* __restrict__ rowptr, const int2* __restrict__ csr2,
    const float* __restrict__ ew, const unsigned short* __restrict__ h,
    const float* __restrict__ bias, void* __restrict__ outv, int N) {
  const int HC = H * C;
  const int G = 64 / L;  // edge groups per wave
  int lane = threadIdx.x & 63;
  int n = blockIdx.x * 4 + (threadIdx.x >> 6);
  if (n >= N) return;
  int l = lane & (L - 1);
  int g = lane / L;
  int c0 = l * 4;
  int hh = c0 / C;
  int beg = rowptr[n];
  int cnt = rowptr[n + 1] - beg;
  float a0 = 0.f, a1 = 0.f, a2 = 0.f, a3 = 0.f, ws = 0.f;

  int j = g;
  for (; j + G < cnt; j += 2 * G) {
    int i0 = beg + j, i1 = beg + j + G;
    int s0 = csr2[i0].x;
    int s1 = csr2[i1].x;
    float w0 = ew[(size_t)i0 * H + hh];
    float w1 = ew[(size_t)i1 * H + hh];
    uint2 u0 = *(const uint2*)(h + (size_t)s0 * HC + c0);
    uint2 u1 = *(const uint2*)(h + (size_t)s1 * HC + c0);
    a0 = fmaf(w0, bflo(u0.x), a0);
    a1 = fmaf(w0, bfhi(u0.x), a1);
    a2 = fmaf(w0, bflo(u0.y), a2);
    a3 = fmaf(w0, bfhi(u0.y), a3);
    a0 = fmaf(w1, bflo(u1.x), a0);
    a1 = fmaf(w1, bfhi(u1.x), a1);
    a2 = fmaf(w1, bflo(u1.y), a2);
    a3 = fmaf(w1, bfhi(u1.y), a3);
    ws += w0 + w1;
  }
  if (j < cnt) {
    int i0 = beg + j;
    int s0 = csr2[i0].x;
    float w0 = ew[(size_t)i0 * H + hh];
    uint2 u0 = *(const uint2*)(h + (size_t)s0 * HC + c0);
    a0 = fmaf(w0, bflo(u0.x), a0);
    a1 = fmaf(w0, bfhi(u0.x), a1);
    a2 = fmaf(w0, bflo(u0.y), a2);
    a3 = fmaf(w0, bfhi(u0.y), a3);
    ws += w0;
  }
#pragma unroll
  for (int off = L; off < 64; off <<= 1) {
    a0 += __shfl_xor(a0, off, 64);
    a1 += __shfl_xor(a1, off, 64);
    a2 += __shfl_xor(a2, off, 64);
    a3 += __shfl_xor(a3, off, 64);
    ws += __shfl_xor(ws, off, 64);
  }
  if (lane < L) {
    float inv = 1.f / ws;  // self-loop guarantees ws > 0
    float v0 = fmaf(a0, inv, bias[c0 + 0]);
    float v1 = fmaf(a1, inv, bias[c0 + 1]);
    float v2 = fmaf(a2, inv, bias[c0 + 2]);
    float v3 = fmaf(a3, inv, bias[c0 + 3]);
    if (OUT_BF16) {
      v0 = fmaxf(v0, 0.f); v1 = fmaxf(v1, 0.f);
      v2 = fmaxf(v2, 0.f); v3 = fmaxf(v3, 0.f);
      unsigned lo = (unsigned)f2bf(v0) | ((unsigned)f2bf(v1) << 16);
      unsigned hi = (unsigned)f2bf(v2) | ((unsigned)f2bf(v3) << 16);
      ((uint2*)outv)[(size_t)n * (HC / 4) + l] = make_uint2(lo, hi);
    } else {
      ((float4*)outv)[(size_t)n * (HC / 4) + l] = make_float4(v0, v1, v2, v3);
    }
  }
}

extern "C" void kernel_launch(void* const* d_in, const int* in_sizes, int n_in,
                              void* d_out, int out_size, void* d_ws, size_t ws_size,
                              hipStream_t stream) {
  const float* x   = (const float*)d_in[0];
  const int*   ei  = (const int*)d_in[1];
  const float* W1  = (const float*)d_in[2];
  const float* as1 = (const float*)d_in[3];
  const float* ad1 = (const float*)d_in[4];
  const float* b1  = (const float*)d_in[5];
  const float* W2  = (const float*)d_in[6];
  const float* as2 = (const float*)d_in[7];
  const float* ad2 = (const float*)d_in[8];
  const float* b2  = (const float*)d_in[9];

  const int N = in_sizes[0] / 128;  // 50000
  const int E = in_sizes[1] / 2;    // 800000
  const int ET = E + N;
  const int NBKT = (N + 255) >> 8;  // 196

  char* pc = (char*)d_ws;
  auto alloc = [&](size_t bytes) -> void* {
    void* r = (void*)pc;
    pc += (bytes + 255) & ~(size_t)255;
    return r;
  };
  unsigned short* h1b   = (unsigned short*)alloc((size_t)N * 128 * 2);  // reused as h2b
  unsigned short* out1b = (unsigned short*)alloc((size_t)N * 128 * 2);
  unsigned short* W1t   = (unsigned short*)alloc(128 * 128 * 2);
  unsigned short* W2t   = (unsigned short*)alloc(64 * 128 * 2);
  float* ssrc1 = (float*)alloc((size_t)N * 4 * 4);
  float* sdst1 = (float*)alloc((size_t)N * 4 * 4);
  float* ssrc2 = (float*)alloc((size_t)N * 4);
  float* sdst2 = (float*)alloc((size_t)N * 4);
  int* rowptr    = (int*)alloc((size_t)(N + 1) * 4);
  int* bucketCnt = (int*)alloc(256 * 4);   // zeroed (with bucketCur)
  int* bucketCur = (int*)alloc(256 * 4);
  int* bucketBase= (int*)alloc(257 * 4);
  int2* bkt   = (int2*)alloc((size_t)ET * 8);
  int2* csr2  = (int2*)alloc((size_t)ET * 8);
  float* ew1  = (float*)alloc((size_t)ET * 4 * 4);
  float* ew2  = (float*)alloc((size_t)ET * 4);
  unsigned short* h2b = h1b;  // alias: h1b dead after layer-1 aggregation

  // zero bucketCnt+bucketCur (adjacent padded allocs; cover the padded span)
  hipMemsetAsync(bucketCnt, 0, (size_t)((char*)bucketBase - (char*)bucketCnt), stream);

  dim3 blk(256);

  // ---- binned CSR build (shared by both layers) ----
  b_hist<<<dim3(64), blk, 0, stream>>>(ei, E, N, bucketCnt);
  b_scan<<<dim3(1), blk, 0, stream>>>(bucketCnt, bucketBase, bucketCur, ET);
  b_binscatter<<<dim3((ET + CHUNK - 1) / CHUNK), blk, 0, stream>>>(
      ei, E, N, bucketBase, bucketCur, bkt);
  b_bucketsort<<<dim3(NBKT), blk, 0, stream>>>(bkt, bucketBase, csr2, rowptr, N, ET);

  cvt_w2<<<dim3((128 * 128 + 128 * 64 + 255) / 256), blk, 0, stream>>>(W1, W1t, W2, W2t);

  // ---- layer 1: 128 -> 4 heads x 32, concat, +bias, ReLU ----
  gemm_mfma<1><<<dim3((N + 63) / 64), blk, 0, stream>>>(x, W1t, h1b, N, 128);
  att_scores_bf<<<dim3((N * 4 + 255) / 256), blk, 0, stream>>>(h1b, as1, ad1, ssrc1, sdst1, N, 4, 32);
  k_weights<4><<<dim3((ET + 255) / 256), blk, 0, stream>>>(csr2, ET, ssrc1, sdst1, ew1);
  gat_aggr3<4, 32, 32, 1><<<dim3((N + 3) / 4), blk, 0, stream>>>(
      rowptr, csr2, ew1, h1b, b1, out1b, N);

  // ---- layer 2: 128 -> 1 head x 64, +bias ----
  gemm_mfma<0><<<dim3((N + 63) / 64), blk, 0, stream>>>(out1b, W2t, h2b, N, 64);
  att_scores_bf<<<dim3((N + 255) / 256), blk, 0, stream>>>(h2b, as2, ad2, ssrc2, sdst2, N, 1, 64);
  k_weights<1><<<dim3((ET + 255) / 256), blk, 0, stream>>>(csr2, ET, ssrc2, sdst2, ew2);
  gat_aggr3<1, 64, 16, 0><<<dim3((N + 3) / 4), blk, 0, stream>>>(
      rowptr, csr2, ew2, h2b, b2, d_out, N);
}

// Round 9
// 260.238 us; speedup vs baseline: 1.2611x; 1.1614x over previous
//
#include <hip/hip_runtime.h>
#include <hip/hip_bf16.h>

// ---------------------------------------------------------------------------
// GAT 2-layer forward. N=50000, E=800000 (+N self loops).
// Round 9: atomic-free parallel CSR build. R8 evidence: b_binscatter ran at
// 1.8% occupancy (52 blocks); shrinking chunks would re-inflate per-bucket
// global-atomic depth. Fix: deterministic 2D scan — per-(block,bucket)
// counts -> per-bucket scan over blocks -> scatter with precomputed offsets
// (zero global atomics, block-private runs). b_hist deleted; all memsets
// deleted (every workspace word written before read).
// Aggregation/GEMM path unchanged from R7/R8. Assumes N <= 65536.
// ---------------------------------------------------------------------------

typedef __attribute__((ext_vector_type(8))) short bf16x8;
typedef __attribute__((ext_vector_type(4))) float f32x4;

#define BCHUNK 2048

__device__ __forceinline__ unsigned short f2bf(float f) {
  unsigned x = __float_as_uint(f);
  unsigned r = (x + 0x7fffu + ((x >> 16) & 1u)) >> 16;  // RNE
  return (unsigned short)r;
}
__device__ __forceinline__ float bflo(unsigned u) {
  return __uint_as_float(u << 16);
}
__device__ __forceinline__ float bfhi(unsigned u) {
  return __uint_as_float(u & 0xffff0000u);
}

// ---- weight conversions: W1[128][128] + W2[128][64] -> bf16 transposed -----
__global__ void cvt_w2(const float* __restrict__ W1, unsigned short* __restrict__ W1t,
                       const float* __restrict__ W2, unsigned short* __restrict__ W2t) {
  int i = blockIdx.x * blockDim.x + threadIdx.x;
  if (i < 128 * 128) {
    int k = i >> 7, m = i & 127;
    W1t[m * 128 + k] = f2bf(W1[i]);
  } else if (i < 128 * 128 + 128 * 64) {
    int j = i - 128 * 128;
    int k = j / 64, m = j % 64;
    W2t[m * 128 + k] = f2bf(W2[j]);
  }
}

// ---- MFMA GEMM: C[N][M] bf16 = A[N][128] @ Bt[M][128]^T --------------------
template <int AF32>
__global__ __launch_bounds__(256) void gemm_mfma(
    const void* __restrict__ Av, const unsigned short* __restrict__ Bt,
    unsigned short* __restrict__ C, int N, int M) {
  const int K = 128;
  int lane = threadIdx.x & 63;
  int wv = threadIdx.x >> 6;
  int row0 = blockIdx.x * 64 + wv * 16;
  if (row0 >= N) return;  // N % 16 == 0
  int r = lane & 15, quad = lane >> 4;

  bf16x8 a[4];
  if (AF32) {
    const float* ap = (const float*)Av + (size_t)(row0 + r) * K + quad * 8;
#pragma unroll
    for (int t = 0; t < 4; ++t) {
      float4 lo = *(const float4*)(ap + t * 32);
      float4 hi = *(const float4*)(ap + t * 32 + 4);
      a[t][0] = (short)f2bf(lo.x); a[t][1] = (short)f2bf(lo.y);
      a[t][2] = (short)f2bf(lo.z); a[t][3] = (short)f2bf(lo.w);
      a[t][4] = (short)f2bf(hi.x); a[t][5] = (short)f2bf(hi.y);
      a[t][6] = (short)f2bf(hi.z); a[t][7] = (short)f2bf(hi.w);
    }
  } else {
    const unsigned short* ap = (const unsigned short*)Av + (size_t)(row0 + r) * K + quad * 8;
#pragma unroll
    for (int t = 0; t < 4; ++t) a[t] = *(const bf16x8*)(ap + t * 32);
  }

  for (int c0 = 0; c0 < M; c0 += 16) {
    f32x4 acc = {0.f, 0.f, 0.f, 0.f};
    const unsigned short* bp = Bt + (size_t)(c0 + r) * K + quad * 8;
#pragma unroll
    for (int t = 0; t < 4; ++t) {
      bf16x8 b = *(const bf16x8*)(bp + t * 32);
      acc = __builtin_amdgcn_mfma_f32_16x16x32_bf16(a[t], b, acc, 0, 0, 0);
    }
    unsigned short* cp = C + (size_t)(row0 + quad * 4) * M + c0 + r;
#pragma unroll
    for (int i = 0; i < 4; ++i) cp[(size_t)i * M] = f2bf(acc[i]);
  }
}

// ---- attention scores (bf16 input) -----------------------------------------
__global__ void att_scores_bf(const unsigned short* __restrict__ h,
                              const float* __restrict__ a_src,
                              const float* __restrict__ a_dst,
                              float* __restrict__ ssrc, float* __restrict__ sdst,
                              int N, int H, int C) {
  int idx = blockIdx.x * blockDim.x + threadIdx.x;
  if (idx >= N * H) return;
  int n = idx / H, hh = idx % H;
  const unsigned short* hp = h + (size_t)n * H * C + (size_t)hh * C;
  const float* as = a_src + hh * C;
  const float* ad = a_dst + hh * C;
  float s1 = 0.f, s2 = 0.f;
  for (int c = 0; c < C; c += 2) {
    unsigned u = *(const unsigned*)(hp + c);
    float f0 = bflo(u), f1 = bfhi(u);
    s1 = fmaf(f0, as[c], fmaf(f1, as[c + 1], s1));
    s2 = fmaf(f0, ad[c], fmaf(f1, ad[c + 1], s2));
  }
  ssrc[idx] = s1;
  sdst[idx] = s2;
}

// ---- atomic-free binned CSR build ------------------------------------------
// bucket b covers dst in [b*256, b*256+256)

// C1: per-(block,bucket) histogram; coalesced store to cnt[blk][256]
__global__ __launch_bounds__(256) void b_count(const int* __restrict__ ei, int E, int N,
                                               int* __restrict__ cnt) {
  __shared__ int h[256];
  int tid = threadIdx.x;
  h[tid] = 0;
  __syncthreads();
  int ET = E + N;
  int base = blockIdx.x * BCHUNK;
  int lim = base + BCHUNK;
  if (lim > ET) lim = ET;
  for (int i = base + tid; i < lim; i += 256) {
    int d = (i < E) ? ei[E + i] : (i - E);
    atomicAdd(&h[d >> 8], 1);
  }
  __syncthreads();
  cnt[(size_t)blockIdx.x * 256 + tid] = h[tid];
}

// C2: per-bucket exclusive scan over blocks: blkoff[blk][bucket], bucketTotal
__global__ __launch_bounds__(256) void b_scan_bkt(const int* __restrict__ cnt, int NBLK,
                                                  int* __restrict__ blkoff,
                                                  int* __restrict__ bucketTotal) {
  __shared__ int s[256];
  int bucket = blockIdx.x, tid = threadIdx.x;
  int carry = 0;
  for (int base = 0; base < NBLK; base += 256) {
    int blk = base + tid;
    int v = (blk < NBLK) ? cnt[(size_t)blk * 256 + bucket] : 0;
    s[tid] = v;
    __syncthreads();
    for (int o = 1; o < 256; o <<= 1) {
      int t = (tid >= o) ? s[tid - o] : 0;
      __syncthreads();
      s[tid] += t;
      __syncthreads();
    }
    if (blk < NBLK) blkoff[(size_t)blk * 256 + bucket] = carry + s[tid] - v;
    carry += s[255];
    __syncthreads();
  }
  if (tid == 0) bucketTotal[bucket] = carry;
}

// C3: single-block exclusive scan of bucketTotal[256] -> bucketBase[257]
__global__ __launch_bounds__(256) void b_scan(const int* __restrict__ bucketTotal,
                                              int* __restrict__ bucketBase, int ET) {
  __shared__ int s[256];
  int tid = threadIdx.x;
  int v = bucketTotal[tid];
  s[tid] = v;
  __syncthreads();
  for (int o = 1; o < 256; o <<= 1) {
    int t = (tid >= o) ? s[tid - o] : 0;
    __syncthreads();
    s[tid] += t;
    __syncthreads();
  }
  bucketBase[tid] = s[tid] - v;
  if (tid == 255) bucketBase[256] = ET;
}

// C4: scatter with precomputed block-private run offsets (no global atomics)
__global__ __launch_bounds__(256) void b_scatter(
    const int* __restrict__ ei, int E, int N,
    const int* __restrict__ bucketBase, const int* __restrict__ blkoff,
    int2* __restrict__ bkt) {
  __shared__ int lcur[256];
  int tid = threadIdx.x;
  lcur[tid] = bucketBase[tid] + blkoff[(size_t)blockIdx.x * 256 + tid];
  __syncthreads();
  int ET = E + N;
  int base = blockIdx.x * BCHUNK;
  int lim = base + BCHUNK;
  if (lim > ET) lim = ET;
  for (int i = base + tid; i < lim; i += 256) {
    int s, d;
    if (i < E) {
      s = ei[i];
      d = ei[E + i];
    } else {
      s = i - E;
      d = s;
    }
    int slot = atomicAdd(&lcur[d >> 8], 1);
    bkt[slot] = make_int2(s, d);
  }
}

// C5: one block per bucket: LDS count+scan over the bucket's 256 nodes,
// coalesced rowptr write, then block-local scatter into csr2.
__global__ __launch_bounds__(256) void b_bucketsort(
    const int2* __restrict__ bkt, const int* __restrict__ bucketBase,
    int2* __restrict__ csr2, int* __restrict__ rowptr, int N, int ET) {
  __shared__ int cnt[256];
  __shared__ int s[256];
  int b = blockIdx.x, tid = threadIdx.x;
  int base = bucketBase[b], end = bucketBase[b + 1];
  cnt[tid] = 0;
  __syncthreads();
  for (int i = base + tid; i < end; i += 256) atomicAdd(&cnt[bkt[i].y & 255], 1);
  __syncthreads();
  int v = cnt[tid];
  s[tid] = v;
  __syncthreads();
  for (int o = 1; o < 256; o <<= 1) {
    int t = (tid >= o) ? s[tid - o] : 0;
    __syncthreads();
    s[tid] += t;
    __syncthreads();
  }
  int excl = s[tid] - v;
  int node = (b << 8) + tid;
  if (node < N) rowptr[node] = base + excl;
  if (tid == 0 && b == gridDim.x - 1) rowptr[N] = ET;
  cnt[tid] = base + excl;  // becomes the scatter cursor
  __syncthreads();
  for (int i = base + tid; i < end; i += 256) {
    int2 p = bkt[i];
    int slot = atomicAdd(&cnt[p.y & 255], 1);
    csr2[slot] = p;
  }
}

// ---- per-(edge,head) softmax weights, coalesced over CSR slots --------------
template <int H>
__global__ void k_weights(const int2* __restrict__ csr2, int ET,
                          const float* __restrict__ ssrc,
                          const float* __restrict__ sdst, float* __restrict__ ew) {
  int i = blockIdx.x * blockDim.x + threadIdx.x;
  if (i >= ET) return;
  int2 p = csr2[i];
  int s = p.x, d = p.y;
  if (H == 4) {
    float4 a = *(const float4*)(ssrc + (size_t)s * 4);
    float4 b = *(const float4*)(sdst + (size_t)d * 4);
    float4 w;
    float sc;
    sc = a.x + b.x; sc = sc > 0.f ? sc : 0.2f * sc; w.x = __expf(sc);
    sc = a.y + b.y; sc = sc > 0.f ? sc : 0.2f * sc; w.y = __expf(sc);
    sc = a.z + b.z; sc = sc > 0.f ? sc : 0.2f * sc; w.z = __expf(sc);
    sc = a.w + b.w; sc = sc > 0.f ? sc : 0.2f * sc; w.w = __expf(sc);
    *(float4*)(ew + (size_t)i * 4) = w;
  } else {
    float sc = ssrc[s] + sdst[d];
    sc = sc > 0.f ? sc : 0.2f * sc;
    ew[i] = __expf(sc);
  }
}

// ---- aggregator: out[n] = (sum_e w_e * h[src_e]) / (sum_e w_e) + bias -------
template <int H, int C, int L, int OUT_BF16>
__global__ __launch_bounds__(256) void gat_aggr3(
    const int* __restrict__ rowptr, const int2* __restrict__ csr2,
    const float* __restrict__ ew, const unsigned short* __restrict__ h,
    const float* __restrict__ bias, void* __restrict__ outv, int N) {
  const int HC = H * C;
  const int G = 64 / L;  // edge groups per wave
  int lane = threadIdx.x & 63;
  int n = blockIdx.x * 4 + (threadIdx.x >> 6);
  if (n >= N) return;
  int l = lane & (L - 1);
  int g = lane / L;
  int c0 = l * 4;
  int hh = c0 / C;
  int beg = rowptr[n];
  int cnt = rowptr[n + 1] - beg;
  float a0 = 0.f, a1 = 0.f, a2 = 0.f, a3 = 0.f, ws = 0.f;

  int j = g;
  for (; j + G < cnt; j += 2 * G) {
    int i0 = beg + j, i1 = beg + j + G;
    int s0 = csr2[i0].x;
    int s1 = csr2[i1].x;
    float w0 = ew[(size_t)i0 * H + hh];
    float w1 = ew[(size_t)i1 * H + hh];
    uint2 u0 = *(const uint2*)(h + (size_t)s0 * HC + c0);
    uint2 u1 = *(const uint2*)(h + (size_t)s1 * HC + c0);
    a0 = fmaf(w0, bflo(u0.x), a0);
    a1 = fmaf(w0, bfhi(u0.x), a1);
    a2 = fmaf(w0, bflo(u0.y), a2);
    a3 = fmaf(w0, bfhi(u0.y), a3);
    a0 = fmaf(w1, bflo(u1.x), a0);
    a1 = fmaf(w1, bfhi(u1.x), a1);
    a2 = fmaf(w1, bflo(u1.y), a2);
    a3 = fmaf(w1, bfhi(u1.y), a3);
    ws += w0 + w1;
  }
  if (j < cnt) {
    int i0 = beg + j;
    int s0 = csr2[i0].x;
    float w0 = ew[(size_t)i0 * H + hh];
    uint2 u0 = *(const uint2*)(h + (size_t)s0 * HC + c0);
    a0 = fmaf(w0, bflo(u0.x), a0);
    a1 = fmaf(w0, bfhi(u0.x), a1);
    a2 = fmaf(w0, bflo(u0.y), a2);
    a3 = fmaf(w0, bfhi(u0.y), a3);
    ws += w0;
  }
#pragma unroll
  for (int off = L; off < 64; off <<= 1) {
    a0 += __shfl_xor(a0, off, 64);
    a1 += __shfl_xor(a1, off, 64);
    a2 += __shfl_xor(a2, off, 64);
    a3 += __shfl_xor(a3, off, 64);
    ws += __shfl_xor(ws, off, 64);
  }
  if (lane < L) {
    float inv = 1.f / ws;  // self-loop guarantees ws > 0
    float v0 = fmaf(a0, inv, bias[c0 + 0]);
    float v1 = fmaf(a1, inv, bias[c0 + 1]);
    float v2 = fmaf(a2, inv, bias[c0 + 2]);
    float v3 = fmaf(a3, inv, bias[c0 + 3]);
    if (OUT_BF16) {
      v0 = fmaxf(v0, 0.f); v1 = fmaxf(v1, 0.f);
      v2 = fmaxf(v2, 0.f); v3 = fmaxf(v3, 0.f);
      unsigned lo = (unsigned)f2bf(v0) | ((unsigned)f2bf(v1) << 16);
      unsigned hi = (unsigned)f2bf(v2) | ((unsigned)f2bf(v3) << 16);
      ((uint2*)outv)[(size_t)n * (HC / 4) + l] = make_uint2(lo, hi);
    } else {
      ((float4*)outv)[(size_t)n * (HC / 4) + l] = make_float4(v0, v1, v2, v3);
    }
  }
}

extern "C" void kernel_launch(void* const* d_in, const int* in_sizes, int n_in,
                              void* d_out, int out_size, void* d_ws, size_t ws_size,
                              hipStream_t stream) {
  const float* x   = (const float*)d_in[0];
  const int*   ei  = (const int*)d_in[1];
  const float* W1  = (const float*)d_in[2];
  const float* as1 = (const float*)d_in[3];
  const float* ad1 = (const float*)d_in[4];
  const float* b1  = (const float*)d_in[5];
  const float* W2  = (const float*)d_in[6];
  const float* as2 = (const float*)d_in[7];
  const float* ad2 = (const float*)d_in[8];
  const float* b2  = (const float*)d_in[9];

  const int N = in_sizes[0] / 128;  // 50000
  const int E = in_sizes[1] / 2;    // 800000
  const int ET = E + N;
  const int NBKT = (N + 255) >> 8;          // 196
  const int NBLK = (ET + BCHUNK - 1) / BCHUNK;  // 416

  char* pc = (char*)d_ws;
  auto alloc = [&](size_t bytes) -> void* {
    void* r = (void*)pc;
    pc += (bytes + 255) & ~(size_t)255;
    return r;
  };
  unsigned short* h1b   = (unsigned short*)alloc((size_t)N * 128 * 2);  // reused as h2b
  unsigned short* out1b = (unsigned short*)alloc((size_t)N * 128 * 2);
  unsigned short* W1t   = (unsigned short*)alloc(128 * 128 * 2);
  unsigned short* W2t   = (unsigned short*)alloc(64 * 128 * 2);
  float* ssrc1 = (float*)alloc((size_t)N * 4 * 4);
  float* sdst1 = (float*)alloc((size_t)N * 4 * 4);
  float* ssrc2 = (float*)alloc((size_t)N * 4);
  float* sdst2 = (float*)alloc((size_t)N * 4);
  int* rowptr      = (int*)alloc((size_t)(N + 1) * 4);
  int* cnt         = (int*)alloc((size_t)NBLK * 256 * 4);
  int* blkoff      = (int*)alloc((size_t)NBLK * 256 * 4);
  int* bucketTotal = (int*)alloc(256 * 4);
  int* bucketBase  = (int*)alloc(257 * 4);
  int2* bkt   = (int2*)alloc((size_t)ET * 8);
  int2* csr2  = (int2*)alloc((size_t)ET * 8);
  float* ew1  = (float*)alloc((size_t)ET * 4 * 4);
  float* ew2  = (float*)alloc((size_t)ET * 4);
  unsigned short* h2b = h1b;  // alias: h1b dead after layer-1 aggregation

  dim3 blk(256);

  // ---- atomic-free binned CSR build (shared by both layers) ----
  b_count<<<dim3(NBLK), blk, 0, stream>>>(ei, E, N, cnt);
  b_scan_bkt<<<dim3(256), blk, 0, stream>>>(cnt, NBLK, blkoff, bucketTotal);
  b_scan<<<dim3(1), blk, 0, stream>>>(bucketTotal, bucketBase, ET);
  b_scatter<<<dim3(NBLK), blk, 0, stream>>>(ei, E, N, bucketBase, blkoff, bkt);
  b_bucketsort<<<dim3(NBKT), blk, 0, stream>>>(bkt, bucketBase, csr2, rowptr, N, ET);

  cvt_w2<<<dim3((128 * 128 + 128 * 64 + 255) / 256), blk, 0, stream>>>(W1, W1t, W2, W2t);

  // ---- layer 1: 128 -> 4 heads x 32, concat, +bias, ReLU ----
  gemm_mfma<1><<<dim3((N + 63) / 64), blk, 0, stream>>>(x, W1t, h1b, N, 128);
  att_scores_bf<<<dim3((N * 4 + 255) / 256), blk, 0, stream>>>(h1b, as1, ad1, ssrc1, sdst1, N, 4, 32);
  k_weights<4><<<dim3((ET + 255) / 256), blk, 0, stream>>>(csr2, ET, ssrc1, sdst1, ew1);
  gat_aggr3<4, 32, 32, 1><<<dim3((N + 3) / 4), blk, 0, stream>>>(
      rowptr, csr2, ew1, h1b, b1, out1b, N);

  // ---- layer 2: 128 -> 1 head x 64, +bias ----
  gemm_mfma<0><<<dim3((N + 63) / 64), blk, 0, stream>>>(out1b, W2t, h2b, N, 64);
  att_scores_bf<<<dim3((N + 255) / 256), blk, 0, stream>>>(h2b, as2, ad2, ssrc2, sdst2, N, 1, 64);
  k_weights<1><<<dim3((ET + 255) / 256), blk, 0, stream>>>(csr2, ET, ssrc2, sdst2, ew2);
  gat_aggr3<1, 64, 16, 0><<<dim3((N + 3) / 4), blk, 0, stream>>>(
      rowptr, csr2, ew2, h2b, b2, d_out, N);
}

// Round 10
// 244.101 us; speedup vs baseline: 1.3445x; 1.0661x over previous
//
#include <hip/hip_runtime.h>
#include <hip/hip_bf16.h>

// ---------------------------------------------------------------------------
// GAT 2-layer forward. N=50000, E=800000 (+N self loops).
// Round 10: R9 profile showed no single kernel >45us (top-5 = harness poison
// fills); distributed reductions: (1) attention scores fused into GEMM via
// pre-projected score weights (s = x @ (W@a)) — att_scores kernels deleted;
// (2) edge weights stored bf16 (halve ew traffic); (3) bkt/csr packed to 4B
// (src|dstLow<<16, src<2^16); (4) int4-vectorized ei reads in build.
// Atomic-free binned CSR build from R9. Assumes N <= 65536.
// ---------------------------------------------------------------------------

typedef __attribute__((ext_vector_type(8))) short bf16x8;
typedef __attribute__((ext_vector_type(4))) float f32x4;

#define BCHUNK 2048

__device__ __forceinline__ unsigned short f2bf(float f) {
  unsigned x = __float_as_uint(f);
  unsigned r = (x + 0x7fffu + ((x >> 16) & 1u)) >> 16;  // RNE
  return (unsigned short)r;
}
__device__ __forceinline__ float bf2f(unsigned short u) {
  return __uint_as_float(((unsigned)u) << 16);
}
__device__ __forceinline__ float bflo(unsigned u) {
  return __uint_as_float(u << 16);
}
__device__ __forceinline__ float bfhi(unsigned u) {
  return __uint_as_float(u & 0xffff0000u);
}

// ---- weight conversion + score-weight pre-projection ------------------------
// W1t[128][128], W2t[64][128] bf16 transposed; wsb1[16][128], wsb2[16][128]
// bf16: wsb1 row m<4 = W1 cols [m*32,m*32+32) . as1[m]; rows 4..7 = ad1; rest 0.
// wsb2 row 0 = W2 . as2, row 1 = W2 . ad2, rest 0.
__global__ void cvt_wall(const float* __restrict__ W1, const float* __restrict__ as1,
                         const float* __restrict__ ad1, const float* __restrict__ W2,
                         const float* __restrict__ as2, const float* __restrict__ ad2,
                         unsigned short* __restrict__ W1t, unsigned short* __restrict__ W2t,
                         unsigned short* __restrict__ wsb1, unsigned short* __restrict__ wsb2) {
  int i = blockIdx.x * blockDim.x + threadIdx.x;
  if (i < 16384) {                       // W1t
    int k = i >> 7, m = i & 127;
    W1t[m * 128 + k] = f2bf(W1[i]);
  } else if (i < 24576) {                // W2t
    int j = i - 16384;
    int k = j / 64, m = j % 64;
    W2t[m * 128 + k] = f2bf(W2[j]);
  } else if (i < 26624) {                // wsb1
    int j = i - 24576;
    int m = j >> 7, k = j & 127;
    float acc = 0.f;
    if (m < 4) {
      for (int c = 0; c < 32; ++c) acc += W1[k * 128 + m * 32 + c] * as1[m * 32 + c];
    } else if (m < 8) {
      for (int c = 0; c < 32; ++c) acc += W1[k * 128 + (m - 4) * 32 + c] * ad1[(m - 4) * 32 + c];
    }
    wsb1[j] = f2bf(acc);
  } else if (i < 28672) {                // wsb2
    int j = i - 26624;
    int m = j >> 7, k = j & 127;
    float acc = 0.f;
    if (m == 0) {
      for (int c = 0; c < 64; ++c) acc += W2[k * 64 + c] * as2[c];
    } else if (m == 1) {
      for (int c = 0; c < 64; ++c) acc += W2[k * 64 + c] * ad2[c];
    }
    wsb2[j] = f2bf(acc);
  }
}

// ---- MFMA GEMM + fused scores: C[N][M] bf16 = A @ Bt^T; scores = A @ wsb ---
// SC = score heads (4: ssrc/sdst [N][4]; 1: [N][1]). wsb rows >= 2*SC are 0.
template <int AF32, int SC>
__global__ __launch_bounds__(256) void gemm_mfma(
    const void* __restrict__ Av, const unsigned short* __restrict__ Bt,
    const unsigned short* __restrict__ wsb, unsigned short* __restrict__ C,
    float* __restrict__ ssrc, float* __restrict__ sdst, int N, int M) {
  const int K = 128;
  int lane = threadIdx.x & 63;
  int wv = threadIdx.x >> 6;
  int row0 = blockIdx.x * 64 + wv * 16;
  if (row0 >= N) return;  // N % 16 == 0
  int r = lane & 15, quad = lane >> 4;

  bf16x8 a[4];
  if (AF32) {
    const float* ap = (const float*)Av + (size_t)(row0 + r) * K + quad * 8;
#pragma unroll
    for (int t = 0; t < 4; ++t) {
      float4 lo = *(const float4*)(ap + t * 32);
      float4 hi = *(const float4*)(ap + t * 32 + 4);
      a[t][0] = (short)f2bf(lo.x); a[t][1] = (short)f2bf(lo.y);
      a[t][2] = (short)f2bf(lo.z); a[t][3] = (short)f2bf(lo.w);
      a[t][4] = (short)f2bf(hi.x); a[t][5] = (short)f2bf(hi.y);
      a[t][6] = (short)f2bf(hi.z); a[t][7] = (short)f2bf(hi.w);
    }
  } else {
    const unsigned short* ap = (const unsigned short*)Av + (size_t)(row0 + r) * K + quad * 8;
#pragma unroll
    for (int t = 0; t < 4; ++t) a[t] = *(const bf16x8*)(ap + t * 32);
  }

  for (int c0 = 0; c0 < M; c0 += 16) {
    f32x4 acc = {0.f, 0.f, 0.f, 0.f};
    const unsigned short* bp = Bt + (size_t)(c0 + r) * K + quad * 8;
#pragma unroll
    for (int t = 0; t < 4; ++t) {
      bf16x8 b = *(const bf16x8*)(bp + t * 32);
      acc = __builtin_amdgcn_mfma_f32_16x16x32_bf16(a[t], b, acc, 0, 0, 0);
    }
    unsigned short* cp = C + (size_t)(row0 + quad * 4) * M + c0 + r;
#pragma unroll
    for (int i = 0; i < 4; ++i) cp[(size_t)i * M] = f2bf(acc[i]);
  }

  // fused score tile: cols are wsb rows (0..SC-1 src, SC..2SC-1 dst)
  {
    f32x4 acc = {0.f, 0.f, 0.f, 0.f};
    const unsigned short* bp = wsb + r * 128 + quad * 8;
#pragma unroll
    for (int t = 0; t < 4; ++t) {
      bf16x8 b = *(const bf16x8*)(bp + t * 32);
      acc = __builtin_amdgcn_mfma_f32_16x16x32_bf16(a[t], b, acc, 0, 0, 0);
    }
    int row = row0 + quad * 4;
    if (r < SC) {
#pragma unroll
      for (int i = 0; i < 4; ++i) ssrc[(size_t)(row + i) * SC + r] = acc[i];
    } else if (r < 2 * SC) {
#pragma unroll
      for (int i = 0; i < 4; ++i) sdst[(size_t)(row + i) * SC + (r - SC)] = acc[i];
    }
  }
}

// ---- atomic-free binned CSR build ------------------------------------------
// bucket b covers dst in [b*256, b*256+256); entry packs src | (dst&255)<<16

// C1: per-(block,bucket) histogram; coalesced store to cnt[blk][256]
__global__ __launch_bounds__(256) void b_count(const int* __restrict__ ei, int E, int N,
                                               int* __restrict__ cnt) {
  __shared__ int h[256];
  int tid = threadIdx.x;
  h[tid] = 0;
  __syncthreads();
  int ET = E + N;
  int base = blockIdx.x * BCHUNK;
  int lim = base + BCHUNK;
  if (lim > ET) lim = ET;
  for (int i = base + tid * 4; i < lim; i += 1024) {
    if (i + 3 < E && i + 4 <= lim) {
      int4 d4 = *(const int4*)(ei + E + i);
      atomicAdd(&h[d4.x >> 8], 1);
      atomicAdd(&h[d4.y >> 8], 1);
      atomicAdd(&h[d4.z >> 8], 1);
      atomicAdd(&h[d4.w >> 8], 1);
    } else {
      for (int k = 0; k < 4; ++k) {
        int idx = i + k;
        if (idx < lim) {
          int d = (idx < E) ? ei[E + idx] : (idx - E);
          atomicAdd(&h[d >> 8], 1);
        }
      }
    }
  }
  __syncthreads();
  cnt[(size_t)blockIdx.x * 256 + tid] = h[tid];
}

// C2: per-bucket exclusive scan over blocks: blkoff[blk][bucket], bucketTotal
__global__ __launch_bounds__(256) void b_scan_bkt(const int* __restrict__ cnt, int NBLK,
                                                  int* __restrict__ blkoff,
                                                  int* __restrict__ bucketTotal) {
  __shared__ int s[256];
  int bucket = blockIdx.x, tid = threadIdx.x;
  int carry = 0;
  for (int base = 0; base < NBLK; base += 256) {
    int blk = base + tid;
    int v = (blk < NBLK) ? cnt[(size_t)blk * 256 + bucket] : 0;
    s[tid] = v;
    __syncthreads();
    for (int o = 1; o < 256; o <<= 1) {
      int t = (tid >= o) ? s[tid - o] : 0;
      __syncthreads();
      s[tid] += t;
      __syncthreads();
    }
    if (blk < NBLK) blkoff[(size_t)blk * 256 + bucket] = carry + s[tid] - v;
    carry += s[255];
    __syncthreads();
  }
  if (tid == 0) bucketTotal[bucket] = carry;
}

// C3: single-block exclusive scan of bucketTotal[256] -> bucketBase[257]
__global__ __launch_bounds__(256) void b_scan(const int* __restrict__ bucketTotal,
                                              int* __restrict__ bucketBase, int ET) {
  __shared__ int s[256];
  int tid = threadIdx.x;
  int v = bucketTotal[tid];
  s[tid] = v;
  __syncthreads();
  for (int o = 1; o < 256; o <<= 1) {
    int t = (tid >= o) ? s[tid - o] : 0;
    __syncthreads();
    s[tid] += t;
    __syncthreads();
  }
  bucketBase[tid] = s[tid] - v;
  if (tid == 255) bucketBase[256] = ET;
}

// C4: scatter packed 4B entries with precomputed block-private run offsets
__global__ __launch_bounds__(256) void b_scatter(
    const int* __restrict__ ei, int E, int N,
    const int* __restrict__ bucketBase, const int* __restrict__ blkoff,
    unsigned* __restrict__ bkt) {
  __shared__ int lcur[256];
  int tid = threadIdx.x;
  lcur[tid] = bucketBase[tid] + blkoff[(size_t)blockIdx.x * 256 + tid];
  __syncthreads();
  int ET = E + N;
  int base = blockIdx.x * BCHUNK;
  int lim = base + BCHUNK;
  if (lim > ET) lim = ET;
  for (int i = base + tid * 4; i < lim; i += 1024) {
    if (i + 3 < E && i + 4 <= lim) {
      int4 s4 = *(const int4*)(ei + i);
      int4 d4 = *(const int4*)(ei + E + i);
      int slot;
      slot = atomicAdd(&lcur[d4.x >> 8], 1); bkt[slot] = (unsigned)s4.x | ((unsigned)(d4.x & 255) << 16);
      slot = atomicAdd(&lcur[d4.y >> 8], 1); bkt[slot] = (unsigned)s4.y | ((unsigned)(d4.y & 255) << 16);
      slot = atomicAdd(&lcur[d4.z >> 8], 1); bkt[slot] = (unsigned)s4.z | ((unsigned)(d4.z & 255) << 16);
      slot = atomicAdd(&lcur[d4.w >> 8], 1); bkt[slot] = (unsigned)s4.w | ((unsigned)(d4.w & 255) << 16);
    } else {
      for (int k = 0; k < 4; ++k) {
        int idx = i + k;
        if (idx < lim) {
          int s, d;
          if (idx < E) { s = ei[idx]; d = ei[E + idx]; }
          else { s = idx - E; d = s; }
          int slot = atomicAdd(&lcur[d >> 8], 1);
          bkt[slot] = (unsigned)s | ((unsigned)(d & 255) << 16);
        }
      }
    }
  }
}

// C5: one block per bucket: LDS count+scan over the bucket's 256 nodes,
// coalesced rowptr write, then block-local scatter into csr4.
__global__ __launch_bounds__(256) void b_bucketsort(
    const unsigned* __restrict__ bkt, const int* __restrict__ bucketBase,
    unsigned* __restrict__ csr4, int* __restrict__ rowptr, int N, int ET) {
  __shared__ int cnt[256];
  __shared__ int s[256];
  int b = blockIdx.x, tid = threadIdx.x;
  int base = bucketBase[b], end = bucketBase[b + 1];
  cnt[tid] = 0;
  __syncthreads();
  for (int i = base + tid; i < end; i += 256) atomicAdd(&cnt[bkt[i] >> 16], 1);
  __syncthreads();
  int v = cnt[tid];
  s[tid] = v;
  __syncthreads();
  for (int o = 1; o < 256; o <<= 1) {
    int t = (tid >= o) ? s[tid - o] : 0;
    __syncthreads();
    s[tid] += t;
    __syncthreads();
  }
  int excl = s[tid] - v;
  int node = (b << 8) + tid;
  if (node < N) rowptr[node] = base + excl;
  if (tid == 0 && b == gridDim.x - 1) rowptr[N] = ET;
  cnt[tid] = base + excl;  // becomes the scatter cursor
  __syncthreads();
  for (int i = base + tid; i < end; i += 256) {
    unsigned p = bkt[i];
    int slot = atomicAdd(&cnt[p >> 16], 1);
    csr4[slot] = p;
  }
}

// ---- per-(edge,head) softmax weights (bf16), one block per bucket ----------
template <int H>
__global__ __launch_bounds__(256) void k_weightsB(
    const unsigned* __restrict__ csr4, const int* __restrict__ bucketBase,
    const float* __restrict__ ssrc, const float* __restrict__ sdst,
    unsigned short* __restrict__ ew) {
  int b = blockIdx.x, tid = threadIdx.x;
  int base = bucketBase[b], end = bucketBase[b + 1];
  for (int i = base + tid; i < end; i += 256) {
    unsigned v = csr4[i];
    int s = v & 0xFFFF;
    int d = (b << 8) | (int)(v >> 16);
    if (H == 4) {
      float4 a = *(const float4*)(ssrc + (size_t)s * 4);
      float4 bb = *(const float4*)(sdst + (size_t)d * 4);
      float sc;
      sc = a.x + bb.x; sc = sc > 0.f ? sc : 0.2f * sc; float w0 = __expf(sc);
      sc = a.y + bb.y; sc = sc > 0.f ? sc : 0.2f * sc; float w1 = __expf(sc);
      sc = a.z + bb.z; sc = sc > 0.f ? sc : 0.2f * sc; float w2 = __expf(sc);
      sc = a.w + bb.w; sc = sc > 0.f ? sc : 0.2f * sc; float w3 = __expf(sc);
      unsigned lo = (unsigned)f2bf(w0) | ((unsigned)f2bf(w1) << 16);
      unsigned hi = (unsigned)f2bf(w2) | ((unsigned)f2bf(w3) << 16);
      *(uint2*)(ew + (size_t)i * 4) = make_uint2(lo, hi);
    } else {
      float sc = ssrc[s] + sdst[d];
      sc = sc > 0.f ? sc : 0.2f * sc;
      ew[i] = f2bf(__expf(sc));
    }
  }
}

// ---- aggregator: out[n] = (sum_e w_e * h[src_e]) / (sum_e w_e) + bias -------
template <int H, int C, int L, int OUT_BF16>
__global__ __launch_bounds__(256) void gat_aggr3(
    const int* __restrict__ rowptr, const unsigned* __restrict__ csr4,
    const unsigned short* __restrict__ ew, const unsigned short* __restrict__ h,
    const float* __restrict__ bias, void* __restrict__ outv, int N) {
  const int HC = H * C;
  const int G = 64 / L;  // edge groups per wave
  int lane = threadIdx.x & 63;
  int n = blockIdx.x * 4 + (threadIdx.x >> 6);
  if (n >= N) return;
  int l = lane & (L - 1);
  int g = lane / L;
  int c0 = l * 4;
  int hh = c0 / C;
  int beg = rowptr[n];
  int cnt = rowptr[n + 1] - beg;
  float a0 = 0.f, a1 = 0.f, a2 = 0.f, a3 = 0.f, ws = 0.f;

  int j = g;
  for (; j + G < cnt; j += 2 * G) {
    int i0 = beg + j, i1 = beg + j + G;
    int s0 = (int)(csr4[i0] & 0xFFFF);
    int s1 = (int)(csr4[i1] & 0xFFFF);
    float w0 = bf2f(ew[(size_t)i0 * H + hh]);
    float w1 = bf2f(ew[(size_t)i1 * H + hh]);
    uint2 u0 = *(const uint2*)(h + (size_t)s0 * HC + c0);
    uint2 u1 = *(const uint2*)(h + (size_t)s1 * HC + c0);
    a0 = fmaf(w0, bflo(u0.x), a0);
    a1 = fmaf(w0, bfhi(u0.x), a1);
    a2 = fmaf(w0, bflo(u0.y), a2);
    a3 = fmaf(w0, bfhi(u0.y), a3);
    a0 = fmaf(w1, bflo(u1.x), a0);
    a1 = fmaf(w1, bfhi(u1.x), a1);
    a2 = fmaf(w1, bflo(u1.y), a2);
    a3 = fmaf(w1, bfhi(u1.y), a3);
    ws += w0 + w1;
  }
  if (j < cnt) {
    int i0 = beg + j;
    int s0 = (int)(csr4[i0] & 0xFFFF);
    float w0 = bf2f(ew[(size_t)i0 * H + hh]);
    uint2 u0 = *(const uint2*)(h + (size_t)s0 * HC + c0);
    a0 = fmaf(w0, bflo(u0.x), a0);
    a1 = fmaf(w0, bfhi(u0.x), a1);
    a2 = fmaf(w0, bflo(u0.y), a2);
    a3 = fmaf(w0, bfhi(u0.y), a3);
    ws += w0;
  }
#pragma unroll
  for (int off = L; off < 64; off <<= 1) {
    a0 += __shfl_xor(a0, off, 64);
    a1 += __shfl_xor(a1, off, 64);
    a2 += __shfl_xor(a2, off, 64);
    a3 += __shfl_xor(a3, off, 64);
    ws += __shfl_xor(ws, off, 64);
  }
  if (lane < L) {
    float inv = 1.f / ws;  // self-loop guarantees ws > 0
    float v0 = fmaf(a0, inv, bias[c0 + 0]);
    float v1 = fmaf(a1, inv, bias[c0 + 1]);
    float v2 = fmaf(a2, inv, bias[c0 + 2]);
    float v3 = fmaf(a3, inv, bias[c0 + 3]);
    if (OUT_BF16) {
      v0 = fmaxf(v0, 0.f); v1 = fmaxf(v1, 0.f);
      v2 = fmaxf(v2, 0.f); v3 = fmaxf(v3, 0.f);
      unsigned lo = (unsigned)f2bf(v0) | ((unsigned)f2bf(v1) << 16);
      unsigned hi = (unsigned)f2bf(v2) | ((unsigned)f2bf(v3) << 16);
      ((uint2*)outv)[(size_t)n * (HC / 4) + l] = make_uint2(lo, hi);
    } else {
      ((float4*)outv)[(size_t)n * (HC / 4) + l] = make_float4(v0, v1, v2, v3);
    }
  }
}

extern "C" void kernel_launch(void* const* d_in, const int* in_sizes, int n_in,
                              void* d_out, int out_size, void* d_ws, size_t ws_size,
                              hipStream_t stream) {
  const float* x   = (const float*)d_in[0];
  const int*   ei  = (const int*)d_in[1];
  const float* W1  = (const float*)d_in[2];
  const float* as1 = (const float*)d_in[3];
  const float* ad1 = (const float*)d_in[4];
  const float* b1  = (const float*)d_in[5];
  const float* W2  = (const float*)d_in[6];
  const float* as2 = (const float*)d_in[7];
  const float* ad2 = (const float*)d_in[8];
  const float* b2  = (const float*)d_in[9];

  const int N = in_sizes[0] / 128;  // 50000
  const int E = in_sizes[1] / 2;    // 800000
  const int ET = E + N;
  const int NBKT = (N + 255) >> 8;              // 196
  const int NBLK = (ET + BCHUNK - 1) / BCHUNK;  // 416

  char* pc = (char*)d_ws;
  auto alloc = [&](size_t bytes) -> void* {
    void* r = (void*)pc;
    pc += (bytes + 255) & ~(size_t)255;
    return r;
  };
  unsigned short* h1b   = (unsigned short*)alloc((size_t)N * 128 * 2);  // reused as h2b
  unsigned short* out1b = (unsigned short*)alloc((size_t)N * 128 * 2);
  unsigned short* W1t   = (unsigned short*)alloc(128 * 128 * 2);
  unsigned short* W2t   = (unsigned short*)alloc(64 * 128 * 2);
  unsigned short* wsb1  = (unsigned short*)alloc(16 * 128 * 2);
  unsigned short* wsb2  = (unsigned short*)alloc(16 * 128 * 2);
  float* ssrc1 = (float*)alloc((size_t)N * 4 * 4);
  float* sdst1 = (float*)alloc((size_t)N * 4 * 4);
  float* ssrc2 = (float*)alloc((size_t)N * 4);
  float* sdst2 = (float*)alloc((size_t)N * 4);
  int* rowptr      = (int*)alloc((size_t)(N + 1) * 4);
  int* cnt         = (int*)alloc((size_t)NBLK * 256 * 4);
  int* blkoff      = (int*)alloc((size_t)NBLK * 256 * 4);
  int* bucketTotal = (int*)alloc(256 * 4);
  int* bucketBase  = (int*)alloc(257 * 4);
  unsigned* bkt  = (unsigned*)alloc((size_t)ET * 4);
  unsigned* csr4 = (unsigned*)alloc((size_t)ET * 4);
  unsigned short* ew1 = (unsigned short*)alloc((size_t)ET * 4 * 2);
  unsigned short* ew2 = (unsigned short*)alloc((size_t)ET * 2);
  unsigned short* h2b = h1b;  // alias: h1b dead after layer-1 aggregation

  dim3 blk(256);

  // ---- atomic-free binned CSR build (shared by both layers) ----
  b_count<<<dim3(NBLK), blk, 0, stream>>>(ei, E, N, cnt);
  b_scan_bkt<<<dim3(256), blk, 0, stream>>>(cnt, NBLK, blkoff, bucketTotal);
  b_scan<<<dim3(1), blk, 0, stream>>>(bucketTotal, bucketBase, ET);
  b_scatter<<<dim3(NBLK), blk, 0, stream>>>(ei, E, N, bucketBase, blkoff, bkt);
  b_bucketsort<<<dim3(NBKT), blk, 0, stream>>>(bkt, bucketBase, csr4, rowptr, N, ET);

  cvt_wall<<<dim3((28672 + 255) / 256), blk, 0, stream>>>(
      W1, as1, ad1, W2, as2, ad2, W1t, W2t, wsb1, wsb2);

  // ---- layer 1: 128 -> 4 heads x 32, concat, +bias, ReLU (scores fused) ----
  gemm_mfma<1, 4><<<dim3((N + 63) / 64), blk, 0, stream>>>(
      x, W1t, wsb1, h1b, ssrc1, sdst1, N, 128);
  k_weightsB<4><<<dim3(NBKT), blk, 0, stream>>>(csr4, bucketBase, ssrc1, sdst1, ew1);
  gat_aggr3<4, 32, 32, 1><<<dim3((N + 3) / 4), blk, 0, stream>>>(
      rowptr, csr4, ew1, h1b, b1, out1b, N);

  // ---- layer 2: 128 -> 1 head x 64, +bias (scores fused) ----
  gemm_mfma<0, 1><<<dim3((N + 63) / 64), blk, 0, stream>>>(
      out1b, W2t, wsb2, h2b, ssrc2, sdst2, N, 64);
  k_weightsB<1><<<dim3(NBKT), blk, 0, stream>>>(csr4, bucketBase, ssrc2, sdst2, ew2);
  gat_aggr3<1, 64, 16, 0><<<dim3((N + 3) / 4), blk, 0, stream>>>(
      rowptr, csr4, ew2, h2b, b2, d_out, N);
}

// Round 11
// 238.677 us; speedup vs baseline: 1.3751x; 1.0227x over previous
//
#include <hip/hip_runtime.h>
#include <hip/hip_bf16.h>

// ---------------------------------------------------------------------------
// GAT 2-layer forward. N=50000, E=800000 (+N self loops).
// Round 11: (1) aggregators gather 8 ch/lane via uint4 (halves VMEM issue in
// the two hottest latency-bound kernels; L1 L=16, L2 L=8); (2) b_scan kernel
// deleted — consumers inline-scan bucketTotal in LDS; (3) BCHUNK 1024 (2x
// build parallelism; offsets precomputed so no atomic cost); (4) 2-deep ILP
// in b_bucketsort passes. Fused-score GEMMs, bf16 ew, packed 4B csr from R10.
// Assumes N <= 65536.
// ---------------------------------------------------------------------------

typedef __attribute__((ext_vector_type(8))) short bf16x8;
typedef __attribute__((ext_vector_type(4))) float f32x4;

#define BCHUNK 1024

__device__ __forceinline__ unsigned short f2bf(float f) {
  unsigned x = __float_as_uint(f);
  unsigned r = (x + 0x7fffu + ((x >> 16) & 1u)) >> 16;  // RNE
  return (unsigned short)r;
}
__device__ __forceinline__ float bf2f(unsigned short u) {
  return __uint_as_float(((unsigned)u) << 16);
}
__device__ __forceinline__ float bflo(unsigned u) {
  return __uint_as_float(u << 16);
}
__device__ __forceinline__ float bfhi(unsigned u) {
  return __uint_as_float(u & 0xffff0000u);
}

// inclusive 256-scan in LDS; returns inclusive sum at tid. Two barriers/step
// (matches the scan used since R8). Caller must __syncthreads() before
// reusing s.
__device__ __forceinline__ int lds_scan256(int v, int* s) {
  int tid = threadIdx.x;
  s[tid] = v;
  __syncthreads();
  for (int o = 1; o < 256; o <<= 1) {
    int t = (tid >= o) ? s[tid - o] : 0;
    __syncthreads();
    s[tid] += t;
    __syncthreads();
  }
  return s[tid];
}

// ---- weight conversion + score-weight pre-projection ------------------------
__global__ void cvt_wall(const float* __restrict__ W1, const float* __restrict__ as1,
                         const float* __restrict__ ad1, const float* __restrict__ W2,
                         const float* __restrict__ as2, const float* __restrict__ ad2,
                         unsigned short* __restrict__ W1t, unsigned short* __restrict__ W2t,
                         unsigned short* __restrict__ wsb1, unsigned short* __restrict__ wsb2) {
  int i = blockIdx.x * blockDim.x + threadIdx.x;
  if (i < 16384) {                       // W1t
    int k = i >> 7, m = i & 127;
    W1t[m * 128 + k] = f2bf(W1[i]);
  } else if (i < 24576) {                // W2t
    int j = i - 16384;
    int k = j / 64, m = j % 64;
    W2t[m * 128 + k] = f2bf(W2[j]);
  } else if (i < 26624) {                // wsb1
    int j = i - 24576;
    int m = j >> 7, k = j & 127;
    float acc = 0.f;
    if (m < 4) {
      for (int c = 0; c < 32; ++c) acc += W1[k * 128 + m * 32 + c] * as1[m * 32 + c];
    } else if (m < 8) {
      for (int c = 0; c < 32; ++c) acc += W1[k * 128 + (m - 4) * 32 + c] * ad1[(m - 4) * 32 + c];
    }
    wsb1[j] = f2bf(acc);
  } else if (i < 28672) {                // wsb2
    int j = i - 26624;
    int m = j >> 7, k = j & 127;
    float acc = 0.f;
    if (m == 0) {
      for (int c = 0; c < 64; ++c) acc += W2[k * 64 + c] * as2[c];
    } else if (m == 1) {
      for (int c = 0; c < 64; ++c) acc += W2[k * 64 + c] * ad2[c];
    }
    wsb2[j] = f2bf(acc);
  }
}

// ---- MFMA GEMM + fused scores: C[N][M] bf16 = A @ Bt^T; scores = A @ wsb ---
template <int AF32, int SC>
__global__ __launch_bounds__(256) void gemm_mfma(
    const void* __restrict__ Av, const unsigned short* __restrict__ Bt,
    const unsigned short* __restrict__ wsb, unsigned short* __restrict__ C,
    float* __restrict__ ssrc, float* __restrict__ sdst, int N, int M) {
  const int K = 128;
  int lane = threadIdx.x & 63;
  int wv = threadIdx.x >> 6;
  int row0 = blockIdx.x * 64 + wv * 16;
  if (row0 >= N) return;  // N % 16 == 0
  int r = lane & 15, quad = lane >> 4;

  bf16x8 a[4];
  if (AF32) {
    const float* ap = (const float*)Av + (size_t)(row0 + r) * K + quad * 8;
#pragma unroll
    for (int t = 0; t < 4; ++t) {
      float4 lo = *(const float4*)(ap + t * 32);
      float4 hi = *(const float4*)(ap + t * 32 + 4);
      a[t][0] = (short)f2bf(lo.x); a[t][1] = (short)f2bf(lo.y);
      a[t][2] = (short)f2bf(lo.z); a[t][3] = (short)f2bf(lo.w);
      a[t][4] = (short)f2bf(hi.x); a[t][5] = (short)f2bf(hi.y);
      a[t][6] = (short)f2bf(hi.z); a[t][7] = (short)f2bf(hi.w);
    }
  } else {
    const unsigned short* ap = (const unsigned short*)Av + (size_t)(row0 + r) * K + quad * 8;
#pragma unroll
    for (int t = 0; t < 4; ++t) a[t] = *(const bf16x8*)(ap + t * 32);
  }

  for (int c0 = 0; c0 < M; c0 += 16) {
    f32x4 acc = {0.f, 0.f, 0.f, 0.f};
    const unsigned short* bp = Bt + (size_t)(c0 + r) * K + quad * 8;
#pragma unroll
    for (int t = 0; t < 4; ++t) {
      bf16x8 b = *(const bf16x8*)(bp + t * 32);
      acc = __builtin_amdgcn_mfma_f32_16x16x32_bf16(a[t], b, acc, 0, 0, 0);
    }
    unsigned short* cp = C + (size_t)(row0 + quad * 4) * M + c0 + r;
#pragma unroll
    for (int i = 0; i < 4; ++i) cp[(size_t)i * M] = f2bf(acc[i]);
  }

  // fused score tile: cols are wsb rows (0..SC-1 src, SC..2SC-1 dst)
  {
    f32x4 acc = {0.f, 0.f, 0.f, 0.f};
    const unsigned short* bp = wsb + r * 128 + quad * 8;
#pragma unroll
    for (int t = 0; t < 4; ++t) {
      bf16x8 b = *(const bf16x8*)(bp + t * 32);
      acc = __builtin_amdgcn_mfma_f32_16x16x32_bf16(a[t], b, acc, 0, 0, 0);
    }
    int row = row0 + quad * 4;
    if (r < SC) {
#pragma unroll
      for (int i = 0; i < 4; ++i) ssrc[(size_t)(row + i) * SC + r] = acc[i];
    } else if (r < 2 * SC) {
#pragma unroll
      for (int i = 0; i < 4; ++i) sdst[(size_t)(row + i) * SC + (r - SC)] = acc[i];
    }
  }
}

// ---- atomic-free binned CSR build ------------------------------------------
// bucket b covers dst in [b*256, b*256+256); entry packs src | (dst&255)<<16

// C1: per-(block,bucket) histogram; coalesced store to cnt[blk][256]
__global__ __launch_bounds__(256) void b_count(const int* __restrict__ ei, int E, int N,
                                               int* __restrict__ cnt) {
  __shared__ int h[256];
  int tid = threadIdx.x;
  h[tid] = 0;
  __syncthreads();
  int ET = E + N;
  int base = blockIdx.x * BCHUNK;
  int lim = base + BCHUNK;
  if (lim > ET) lim = ET;
  for (int i = base + tid * 4; i < lim; i += 1024) {
    if (i + 3 < E && i + 4 <= lim) {
      int4 d4 = *(const int4*)(ei + E + i);
      atomicAdd(&h[d4.x >> 8], 1);
      atomicAdd(&h[d4.y >> 8], 1);
      atomicAdd(&h[d4.z >> 8], 1);
      atomicAdd(&h[d4.w >> 8], 1);
    } else {
      for (int k = 0; k < 4; ++k) {
        int idx = i + k;
        if (idx < lim) {
          int d = (idx < E) ? ei[E + idx] : (idx - E);
          atomicAdd(&h[d >> 8], 1);
        }
      }
    }
  }
  __syncthreads();
  cnt[(size_t)blockIdx.x * 256 + tid] = h[tid];
}

// C2: per-bucket exclusive scan over blocks: blkoff[blk][bucket], bucketTotal
__global__ __launch_bounds__(256) void b_scan_bkt(const int* __restrict__ cnt, int NBLK,
                                                  int* __restrict__ blkoff,
                                                  int* __restrict__ bucketTotal) {
  __shared__ int s[256];
  int bucket = blockIdx.x, tid = threadIdx.x;
  int carry = 0;
  for (int base = 0; base < NBLK; base += 256) {
    int blk = base + tid;
    int v = (blk < NBLK) ? cnt[(size_t)blk * 256 + bucket] : 0;
    s[tid] = v;
    __syncthreads();
    for (int o = 1; o < 256; o <<= 1) {
      int t = (tid >= o) ? s[tid - o] : 0;
      __syncthreads();
      s[tid] += t;
      __syncthreads();
    }
    if (blk < NBLK) blkoff[(size_t)blk * 256 + bucket] = carry + s[tid] - v;
    carry += s[255];
    __syncthreads();
  }
  if (tid == 0) bucketTotal[bucket] = carry;
}

// C3: scatter packed 4B entries; bucket bases recomputed by inline LDS scan
__global__ __launch_bounds__(256) void b_scatter(
    const int* __restrict__ ei, int E, int N,
    const int* __restrict__ bucketTotal, const int* __restrict__ blkoff,
    unsigned* __restrict__ bkt) {
  __shared__ int s[256];
  __shared__ int lcur[256];
  int tid = threadIdx.x;
  int tot = bucketTotal[tid];
  int incl = lds_scan256(tot, s);
  lcur[tid] = (incl - tot) + blkoff[(size_t)blockIdx.x * 256 + tid];
  __syncthreads();
  int ET = E + N;
  int base = blockIdx.x * BCHUNK;
  int lim = base + BCHUNK;
  if (lim > ET) lim = ET;
  for (int i = base + tid * 4; i < lim; i += 1024) {
    if (i + 3 < E && i + 4 <= lim) {
      int4 s4 = *(const int4*)(ei + i);
      int4 d4 = *(const int4*)(ei + E + i);
      int slot;
      slot = atomicAdd(&lcur[d4.x >> 8], 1); bkt[slot] = (unsigned)s4.x | ((unsigned)(d4.x & 255) << 16);
      slot = atomicAdd(&lcur[d4.y >> 8], 1); bkt[slot] = (unsigned)s4.y | ((unsigned)(d4.y & 255) << 16);
      slot = atomicAdd(&lcur[d4.z >> 8], 1); bkt[slot] = (unsigned)s4.z | ((unsigned)(d4.z & 255) << 16);
      slot = atomicAdd(&lcur[d4.w >> 8], 1); bkt[slot] = (unsigned)s4.w | ((unsigned)(d4.w & 255) << 16);
    } else {
      for (int k = 0; k < 4; ++k) {
        int idx = i + k;
        if (idx < lim) {
          int s_, d;
          if (idx < E) { s_ = ei[idx]; d = ei[E + idx]; }
          else { s_ = idx - E; d = s_; }
          int slot = atomicAdd(&lcur[d >> 8], 1);
          bkt[slot] = (unsigned)s_ | ((unsigned)(d & 255) << 16);
        }
      }
    }
  }
}

// C4: one block per bucket: LDS count+scan over the bucket's 256 nodes,
// coalesced rowptr write, block-local scatter into csr4. 2-deep ILP passes.
__global__ __launch_bounds__(256) void b_bucketsort(
    const unsigned* __restrict__ bkt, const int* __restrict__ bucketTotal,
    unsigned* __restrict__ csr4, int* __restrict__ rowptr, int N, int ET) {
  __shared__ int s[256];
  __shared__ int cnt[256];
  int b = blockIdx.x, tid = threadIdx.x;
  int tot = bucketTotal[tid];
  (void)lds_scan256(tot, s);  // s[i] = inclusive sum
  int base = (b == 0) ? 0 : s[b - 1];
  int end = s[b];
  __syncthreads();  // done reading s from bucket scan
  cnt[tid] = 0;
  __syncthreads();
  for (int i = base + tid; i < end; i += 512) {
    unsigned p0 = bkt[i];
    int i1 = i + 256;
    unsigned p1 = (i1 < end) ? bkt[i1] : 0u;
    atomicAdd(&cnt[p0 >> 16], 1);
    if (i1 < end) atomicAdd(&cnt[p1 >> 16], 1);
  }
  __syncthreads();
  int v = cnt[tid];
  int incl = lds_scan256(v, s);
  int excl = incl - v;
  int node = (b << 8) + tid;
  if (node < N) rowptr[node] = base + excl;
  if (tid == 0 && b == gridDim.x - 1) rowptr[N] = ET;
  cnt[tid] = base + excl;  // becomes the scatter cursor
  __syncthreads();
  for (int i = base + tid; i < end; i += 512) {
    unsigned p0 = bkt[i];
    int i1 = i + 256;
    unsigned p1 = (i1 < end) ? bkt[i1] : 0u;
    int slot0 = atomicAdd(&cnt[p0 >> 16], 1);
    csr4[slot0] = p0;
    if (i1 < end) {
      int slot1 = atomicAdd(&cnt[p1 >> 16], 1);
      csr4[slot1] = p1;
    }
  }
}

// ---- per-(edge,head) softmax weights (bf16), one block per bucket ----------
template <int H>
__global__ __launch_bounds__(256) void k_weightsB(
    const unsigned* __restrict__ csr4, const int* __restrict__ bucketTotal,
    const float* __restrict__ ssrc, const float* __restrict__ sdst,
    unsigned short* __restrict__ ew) {
  __shared__ int s[256];
  int b = blockIdx.x, tid = threadIdx.x;
  int tot = bucketTotal[tid];
  (void)lds_scan256(tot, s);
  int base = (b == 0) ? 0 : s[b - 1];
  int end = s[b];
  __syncthreads();
  for (int i = base + tid; i < end; i += 256) {
    unsigned v = csr4[i];
    int src = v & 0xFFFF;
    int d = (b << 8) | (int)(v >> 16);
    if (H == 4) {
      float4 a = *(const float4*)(ssrc + (size_t)src * 4);
      float4 bb = *(const float4*)(sdst + (size_t)d * 4);
      float sc;
      sc = a.x + bb.x; sc = sc > 0.f ? sc : 0.2f * sc; float w0 = __expf(sc);
      sc = a.y + bb.y; sc = sc > 0.f ? sc : 0.2f * sc; float w1 = __expf(sc);
      sc = a.z + bb.z; sc = sc > 0.f ? sc : 0.2f * sc; float w2 = __expf(sc);
      sc = a.w + bb.w; sc = sc > 0.f ? sc : 0.2f * sc; float w3 = __expf(sc);
      unsigned lo = (unsigned)f2bf(w0) | ((unsigned)f2bf(w1) << 16);
      unsigned hi = (unsigned)f2bf(w2) | ((unsigned)f2bf(w3) << 16);
      *(uint2*)(ew + (size_t)i * 4) = make_uint2(lo, hi);
    } else {
      float sc = ssrc[src] + sdst[d];
      sc = sc > 0.f ? sc : 0.2f * sc;
      ew[i] = f2bf(__expf(sc));
    }
  }
}

// ---- aggregator: out[n] = (sum_e w_e * h[src_e]) / (sum_e w_e) + bias -------
// One wave per dst node. L lanes/edge, 8 bf16 channels/lane (uint4 gather);
// G=64/L edge groups in flight. Cross-group combine via shfl_xor butterfly.
template <int H, int C, int L, int OUT_BF16>
__global__ __launch_bounds__(256) void gat_aggr4(
    const int* __restrict__ rowptr, const unsigned* __restrict__ csr4,
    const unsigned short* __restrict__ ew, const unsigned short* __restrict__ h,
    const float* __restrict__ bias, void* __restrict__ outv, int N) {
  const int HC = H * C;  // = 8*L
  const int G = 64 / L;
  int lane = threadIdx.x & 63;
  int n = blockIdx.x * 4 + (threadIdx.x >> 6);
  if (n >= N) return;
  int l = lane & (L - 1);
  int g = lane / L;
  int c0 = l * 8;
  int hh = c0 / C;
  int beg = rowptr[n];
  int cnt = rowptr[n + 1] - beg;
  float a0 = 0.f, a1 = 0.f, a2 = 0.f, a3 = 0.f;
  float a4 = 0.f, a5 = 0.f, a6 = 0.f, a7 = 0.f, ws = 0.f;

  int j = g;
  for (; j + G < cnt; j += 2 * G) {
    int i0 = beg + j, i1 = beg + j + G;
    int s0 = (int)(csr4[i0] & 0xFFFF);
    int s1 = (int)(csr4[i1] & 0xFFFF);
    float w0 = bf2f(ew[(size_t)i0 * H + hh]);
    float w1 = bf2f(ew[(size_t)i1 * H + hh]);
    uint4 u0 = *(const uint4*)(h + (size_t)s0 * HC + c0);
    uint4 u1 = *(const uint4*)(h + (size_t)s1 * HC + c0);
    a0 = fmaf(w0, bflo(u0.x), a0); a1 = fmaf(w0, bfhi(u0.x), a1);
    a2 = fmaf(w0, bflo(u0.y), a2); a3 = fmaf(w0, bfhi(u0.y), a3);
    a4 = fmaf(w0, bflo(u0.z), a4); a5 = fmaf(w0, bfhi(u0.z), a5);
    a6 = fmaf(w0, bflo(u0.w), a6); a7 = fmaf(w0, bfhi(u0.w), a7);
    a0 = fmaf(w1, bflo(u1.x), a0); a1 = fmaf(w1, bfhi(u1.x), a1);
    a2 = fmaf(w1, bflo(u1.y), a2); a3 = fmaf(w1, bfhi(u1.y), a3);
    a4 = fmaf(w1, bflo(u1.z), a4); a5 = fmaf(w1, bfhi(u1.z), a5);
    a6 = fmaf(w1, bflo(u1.w), a6); a7 = fmaf(w1, bfhi(u1.w), a7);
    ws += w0 + w1;
  }
  if (j < cnt) {
    int i0 = beg + j;
    int s0 = (int)(csr4[i0] & 0xFFFF);
    float w0 = bf2f(ew[(size_t)i0 * H + hh]);
    uint4 u0 = *(const uint4*)(h + (size_t)s0 * HC + c0);
    a0 = fmaf(w0, bflo(u0.x), a0); a1 = fmaf(w0, bfhi(u0.x), a1);
    a2 = fmaf(w0, bflo(u0.y), a2); a3 = fmaf(w0, bfhi(u0.y), a3);
    a4 = fmaf(w0, bflo(u0.z), a4); a5 = fmaf(w0, bfhi(u0.z), a5);
    a6 = fmaf(w0, bflo(u0.w), a6); a7 = fmaf(w0, bfhi(u0.w), a7);
    ws += w0;
  }
#pragma unroll
  for (int off = L; off < 64; off <<= 1) {
    a0 += __shfl_xor(a0, off, 64); a1 += __shfl_xor(a1, off, 64);
    a2 += __shfl_xor(a2, off, 64); a3 += __shfl_xor(a3, off, 64);
    a4 += __shfl_xor(a4, off, 64); a5 += __shfl_xor(a5, off, 64);
    a6 += __shfl_xor(a6, off, 64); a7 += __shfl_xor(a7, off, 64);
    ws += __shfl_xor(ws, off, 64);
  }
  if (lane < L) {
    float inv = 1.f / ws;  // self-loop guarantees ws > 0
    float4 bA = *(const float4*)(bias + c0);
    float4 bB = *(const float4*)(bias + c0 + 4);
    float v0 = fmaf(a0, inv, bA.x), v1 = fmaf(a1, inv, bA.y);
    float v2 = fmaf(a2, inv, bA.z), v3 = fmaf(a3, inv, bA.w);
    float v4 = fmaf(a4, inv, bB.x), v5 = fmaf(a5, inv, bB.y);
    float v6 = fmaf(a6, inv, bB.z), v7 = fmaf(a7, inv, bB.w);
    if (OUT_BF16) {
      v0 = fmaxf(v0, 0.f); v1 = fmaxf(v1, 0.f);
      v2 = fmaxf(v2, 0.f); v3 = fmaxf(v3, 0.f);
      v4 = fmaxf(v4, 0.f); v5 = fmaxf(v5, 0.f);
      v6 = fmaxf(v6, 0.f); v7 = fmaxf(v7, 0.f);
      uint4 o;
      o.x = (unsigned)f2bf(v0) | ((unsigned)f2bf(v1) << 16);
      o.y = (unsigned)f2bf(v2) | ((unsigned)f2bf(v3) << 16);
      o.z = (unsigned)f2bf(v4) | ((unsigned)f2bf(v5) << 16);
      o.w = (unsigned)f2bf(v6) | ((unsigned)f2bf(v7) << 16);
      ((uint4*)outv)[(size_t)n * (HC / 8) + l] = o;
    } else {
      float* op = (float*)outv + (size_t)n * HC + c0;
      *(float4*)op = make_float4(v0, v1, v2, v3);
      *(float4*)(op + 4) = make_float4(v4, v5, v6, v7);
    }
  }
}

extern "C" void kernel_launch(void* const* d_in, const int* in_sizes, int n_in,
                              void* d_out, int out_size, void* d_ws, size_t ws_size,
                              hipStream_t stream) {
  const float* x   = (const float*)d_in[0];
  const int*   ei  = (const int*)d_in[1];
  const float* W1  = (const float*)d_in[2];
  const float* as1 = (const float*)d_in[3];
  const float* ad1 = (const float*)d_in[4];
  const float* b1  = (const float*)d_in[5];
  const float* W2  = (const float*)d_in[6];
  const float* as2 = (const float*)d_in[7];
  const float* ad2 = (const float*)d_in[8];
  const float* b2  = (const float*)d_in[9];

  const int N = in_sizes[0] / 128;  // 50000
  const int E = in_sizes[1] / 2;    // 800000
  const int ET = E + N;
  const int NBKT = (N + 255) >> 8;              // 196
  const int NBLK = (ET + BCHUNK - 1) / BCHUNK;  // 831

  char* pc = (char*)d_ws;
  auto alloc = [&](size_t bytes) -> void* {
    void* r = (void*)pc;
    pc += (bytes + 255) & ~(size_t)255;
    return r;
  };
  unsigned short* h1b   = (unsigned short*)alloc((size_t)N * 128 * 2);  // reused as h2b
  unsigned short* out1b = (unsigned short*)alloc((size_t)N * 128 * 2);
  unsigned short* W1t   = (unsigned short*)alloc(128 * 128 * 2);
  unsigned short* W2t   = (unsigned short*)alloc(64 * 128 * 2);
  unsigned short* wsb1  = (unsigned short*)alloc(16 * 128 * 2);
  unsigned short* wsb2  = (unsigned short*)alloc(16 * 128 * 2);
  float* ssrc1 = (float*)alloc((size_t)N * 4 * 4);
  float* sdst1 = (float*)alloc((size_t)N * 4 * 4);
  float* ssrc2 = (float*)alloc((size_t)N * 4);
  float* sdst2 = (float*)alloc((size_t)N * 4);
  int* rowptr      = (int*)alloc((size_t)(N + 1) * 4);
  int* cnt         = (int*)alloc((size_t)NBLK * 256 * 4);
  int* blkoff      = (int*)alloc((size_t)NBLK * 256 * 4);
  int* bucketTotal = (int*)alloc(256 * 4);
  unsigned* bkt  = (unsigned*)alloc((size_t)ET * 4);
  unsigned* csr4 = (unsigned*)alloc((size_t)ET * 4);
  unsigned short* ew1 = (unsigned short*)alloc((size_t)ET * 4 * 2);
  unsigned short* ew2 = (unsigned short*)alloc((size_t)ET * 2);
  unsigned short* h2b = h1b;  // alias: h1b dead after layer-1 aggregation

  dim3 blk(256);

  // ---- atomic-free binned CSR build (shared by both layers) ----
  b_count<<<dim3(NBLK), blk, 0, stream>>>(ei, E, N, cnt);
  b_scan_bkt<<<dim3(256), blk, 0, stream>>>(cnt, NBLK, blkoff, bucketTotal);
  b_scatter<<<dim3(NBLK), blk, 0, stream>>>(ei, E, N, bucketTotal, blkoff, bkt);
  b_bucketsort<<<dim3(NBKT), blk, 0, stream>>>(bkt, bucketTotal, csr4, rowptr, N, ET);

  cvt_wall<<<dim3((28672 + 255) / 256), blk, 0, stream>>>(
      W1, as1, ad1, W2, as2, ad2, W1t, W2t, wsb1, wsb2);

  // ---- layer 1: 128 -> 4 heads x 32, concat, +bias, ReLU (scores fused) ----
  gemm_mfma<1, 4><<<dim3((N + 63) / 64), blk, 0, stream>>>(
      x, W1t, wsb1, h1b, ssrc1, sdst1, N, 128);
  k_weightsB<4><<<dim3(NBKT), blk, 0, stream>>>(csr4, bucketTotal, ssrc1, sdst1, ew1);
  gat_aggr4<4, 32, 16, 1><<<dim3((N + 3) / 4), blk, 0, stream>>>(
      rowptr, csr4, ew1, h1b, b1, out1b, N);

  // ---- layer 2: 128 -> 1 head x 64, +bias (scores fused) ----
  gemm_mfma<0, 1><<<dim3((N + 63) / 64), blk, 0, stream>>>(
      out1b, W2t, wsb2, h2b, ssrc2, sdst2, N, 64);
  k_weightsB<1><<<dim3(NBKT), blk, 0, stream>>>(csr4, bucketTotal, ssrc2, sdst2, ew2);
  gat_aggr4<1, 64, 8, 0><<<dim3((N + 3) / 4), blk, 0, stream>>>(
      rowptr, csr4, ew2, h2b, b2, d_out, N);
}